// Round 8
// baseline (1174.082 us; speedup 1.0000x reference)
//
#include <hip/hip_runtime.h>
#include <cstdint>
#include <cstddef>

#define Bq  16
#define Sq  512
#define Dq  768
#define Hq  12
#define DHq 64
#define Fq  3072
#define SWq 128
#define NTq 8192

typedef float        f32x4  __attribute__((ext_vector_type(4)));
typedef float        f32x16 __attribute__((ext_vector_type(16)));
typedef unsigned int u32x4  __attribute__((ext_vector_type(4)));
typedef __bf16       bf16x8 __attribute__((ext_vector_type(8)));
typedef _Float16     f16x8  __attribute__((ext_vector_type(8)));
typedef _Float16     f16x4  __attribute__((ext_vector_type(4)));
typedef _Float16     f16x2  __attribute__((ext_vector_type(2)));
typedef int          i32x2  __attribute__((ext_vector_type(2)));

__device__ __forceinline__ unsigned short f2bf(float f){
  unsigned int u = __builtin_bit_cast(unsigned int, f);
  u = (u + 0x7fffu + ((u >> 16) & 1u)) >> 16;
  return (unsigned short)u;
}
__device__ __forceinline__ unsigned int pk2(float a, float b){
  return (unsigned int)f2bf(a) | ((unsigned int)f2bf(b) << 16);
}
__device__ __forceinline__ i32x2 pl32swap(unsigned int a, unsigned int b){
  return __builtin_amdgcn_permlane32_swap((int)a, (int)b, false, false);
}
__device__ __forceinline__ f16x2 cvt_pk(float a, float b){
  return __builtin_bit_cast(f16x2, __builtin_amdgcn_cvt_pkrtz(a, b));
}

// async global->LDS DMA, 16B per lane. LDS dest = wave-uniform base + lane*16.
typedef __attribute__((address_space(1))) void vg_t;
typedef __attribute__((address_space(3))) void vl_t;
__device__ __forceinline__ void gl_lds16(const void* g, void* l){
  __builtin_amdgcn_global_load_lds((vg_t*)g, (vl_t*)l, 16, 0, 0);
}

// Band-supertile + XCD-aware bijective block remap (non-grouped GEMMs).
__device__ __forceinline__ void swz2d(int &bx, int &by){
  const int gx = gridDim.x, gy = gridDim.y;
  const int nb = gx * gy;
  const int bid = blockIdx.y * gx + blockIdx.x;
  if (((nb & 7) == 0) && ((gy & 7) == 0)){
    const int chunk = nb >> 3;
    const int lb = (bid & 7) * chunk + (bid >> 3);
    const int bw = gx << 3;              // blocks per band
    const int band = lb / bw;
    const int wn = lb - band * bw;
    bx = wn >> 3;
    by = (band << 3) + (wn & 7);
  } else {
    bx = blockIdx.x; by = blockIdx.y;
  }
}

// ---------------- pooled partial sums (seq router input) ----------------
__global__ void pooled_partial_k(const float* __restrict__ x, float* __restrict__ part){
  const int b = blockIdx.x, dc = blockIdx.y, z = blockIdx.z;
  const int d = dc*256 + threadIdx.x;
  const float* p = x + (size_t)b*Sq*Dq + (size_t)z*128*Dq + d;
  float s = 0.f;
  #pragma unroll 4
  for (int i = 0; i < 128; i++) s += p[(size_t)i*Dq];
  part[((size_t)z*Bq + b)*Dq + d] = s;
}

// ---------------- sequence-level router (exact f32) ----------------
__global__ void router_seq_k(const float* __restrict__ part,
    const float* __restrict__ ew, const float* __restrict__ eb,
    const float* __restrict__ sw, const float* __restrict__ sb,
    int* __restrict__ sel, float* __restrict__ pm)
{
  const int b = blockIdx.x, j = threadIdx.x;   // 128 threads
  __shared__ float h[SWq];
  __shared__ float pl[Dq];
  #pragma unroll
  for (int i = 0; i < 6; i++){
    int d = j + i*128;
    float s = part[(size_t)(0*Bq+b)*Dq + d] + part[(size_t)(1*Bq+b)*Dq + d]
            + part[(size_t)(2*Bq+b)*Dq + d] + part[(size_t)(3*Bq+b)*Dq + d];
    pl[d] = s * (1.0f/512.0f);
  }
  __syncthreads();
  float a = eb[j];
  for (int d = 0; d < Dq; d++) a += pl[d] * ew[d*SWq + j];
  h[j] = a;
  __syncthreads();
  if (j == 0){
    float lg[4];
    for (int e = 0; e < 4; e++){
      float t = sb[e];
      for (int k = 0; k < SWq; k++) t += h[k] * sw[k*4 + e];
      lg[e] = t;
    }
    float mx = fmaxf(fmaxf(lg[0],lg[1]), fmaxf(lg[2],lg[3]));
    float p[4], ssum = 0.f;
    for (int e = 0; e < 4; e++){ p[e] = expf(lg[e]-mx); ssum += p[e]; }
    int am = 0; float bv = p[0];
    for (int e = 1; e < 4; e++) if (p[e] > bv){ bv = p[e]; am = e; }
    sel[b] = am; pm[b] = bv/ssum;
  }
}

// ---------------- f32 -> f16 hi/lo split (x1024 scale) ----------------
__global__ void split_f16_k(const float* __restrict__ x, _Float16* __restrict__ hh,
                            _Float16* __restrict__ ll, int n4){
  const int i = blockIdx.x*256 + threadIdx.x;
  if (i >= n4) return;
  f32x4 v = ((const f32x4*)x)[i];
  f16x4 vh, vl;
  #pragma unroll
  for (int j = 0; j < 4; j++){
    float s = v[j] * 1024.0f;
    _Float16 a = (_Float16)s;
    vh[j] = a;
    vl[j] = (_Float16)(s - (float)a);
  }
  ((f16x4*)hh)[i] = vh;
  ((f16x4*)ll)[i] = vl;
}

// ------- weight transpose + f16 hi/lo split: src [K][N] -> dst [N][K] x1024 -------
__global__ void transpose_f16s_k(const float* __restrict__ src,
    _Float16* __restrict__ dH, _Float16* __restrict__ dL,
    int K, int N, long srcStride, long dstStride, int rowOff)
{
  __shared__ float t[64][65];
  const int tid = threadIdx.x;
  const size_t so = (size_t)blockIdx.z * srcStride;
  const size_t dof = (size_t)blockIdx.z * dstStride;
  const int k0 = blockIdx.y * 64, n0 = blockIdx.x * 64;
  const int r = tid >> 2, c0 = (tid & 3) * 16;
  const float* sp = src + so + (size_t)(k0 + r) * N + n0 + c0;
  #pragma unroll
  for (int cc = 0; cc < 16; cc += 4){
    f32x4 v = *(const f32x4*)(sp + cc);
    t[r][c0+cc] = v[0]; t[r][c0+cc+1] = v[1]; t[r][c0+cc+2] = v[2]; t[r][c0+cc+3] = v[3];
  }
  __syncthreads();
  _Float16* ph = dH + dof + (size_t)(rowOff + n0 + r) * K + k0 + c0;
  _Float16* pl = dL + dof + (size_t)(rowOff + n0 + r) * K + k0 + c0;
  #pragma unroll
  for (int cc = 0; cc < 16; cc += 4){
    f16x4 vh, vl;
    #pragma unroll
    for (int j = 0; j < 4; j++){
      float s = t[c0+cc+j][r] * 1024.0f;
      _Float16 a = (_Float16)s;
      vh[j] = a; vl[j] = (_Float16)(s - (float)a);
    }
    *(f16x4*)(ph + cc) = vh;
    *(f16x4*)(pl + cc) = vl;
  }
}

// ---------------- concat q/k/v biases -> [E][2304] ----------------
__global__ void concat_bias3_k(const float* __restrict__ bq, const float* __restrict__ bk,
    const float* __restrict__ bv, float* __restrict__ dst, int srcStride)
{
  const int e = blockIdx.y;
  const int i = blockIdx.x*256 + threadIdx.x;   // grid.x=3 -> i<768
  dst[(size_t)e*2304 + i]        = bq[(size_t)e*srcStride + i];
  dst[(size_t)e*2304 + 768 + i]  = bk[(size_t)e*srcStride + i];
  dst[(size_t)e*2304 + 1536 + i] = bv[(size_t)e*srcStride + i];
}

// ------- split-f16 3-term MFMA GEMM, double-buffered global_load_lds staging -------
template<int BMODE, int OMODE>
__global__ __launch_bounds__(256,2) void gemm_f16s_k(
    const _Float16* __restrict__ AH, const _Float16* __restrict__ AL,
    const _Float16* __restrict__ BH, const _Float16* __restrict__ BL,
    const float* __restrict__ bias, float* __restrict__ C,
    _Float16* __restrict__ Ch, _Float16* __restrict__ Cl,
    int N, int K, long estride, int bias_stride,
    const int* __restrict__ sel, const float* __restrict__ pm)
{
  __shared__ _Float16 AsH[2][128][32];
  __shared__ _Float16 AsL[2][128][32];
  __shared__ _Float16 BsH[2][128][32];
  __shared__ _Float16 BsL[2][128][32];
  const int tid = threadIdx.x;
  const int lane = tid & 63, wave = tid >> 6;
  const int wm = wave >> 1, wn = wave & 1;
  int bx, by; swz2d(bx, by);
  const int row0 = by * 128, col0 = bx * 128;
  const _Float16* bh = BH; const _Float16* bl = BL; const float* bp = bias;
  float cs = 1.0f;
  if constexpr (BMODE == 1){
    const int e = sel[row0 >> 9];
    bh += (size_t)e * estride; bl += (size_t)e * estride;
    bp += (size_t)e * bias_stride;
  }
  if constexpr (OMODE == 1) cs = pm[row0 >> 9];

  // DMA staging: tile 128x32 f16 = 8KB = 8 x 1KB instrs; wave w issues j=0,1 per tile.
  const int lr = lane >> 2, lk = (lane & 3) * 8;
  const _Float16 *pAH[2], *pAL[2], *pBH[2], *pBL[2];
  #pragma unroll
  for (int j = 0; j < 2; j++){
    const int ia = wave*2 + j;
    pAH[j] = AH + (size_t)(row0 + ia*16 + lr)*K + lk;
    pAL[j] = AL + (size_t)(row0 + ia*16 + lr)*K + lk;
    pBH[j] = bh + (size_t)(col0 + ia*16 + lr)*K + lk;
    pBL[j] = bl + (size_t)(col0 + ia*16 + lr)*K + lk;
  }
  auto stage = [&](int c, int kk){
    #pragma unroll
    for (int j = 0; j < 2; j++){
      const int ia = wave*2 + j;
      gl_lds16(pAH[j] + kk, &AsH[0][0][0] + c*4096 + ia*512);
      gl_lds16(pAL[j] + kk, &AsL[0][0][0] + c*4096 + ia*512);
      gl_lds16(pBH[j] + kk, &BsH[0][0][0] + c*4096 + ia*512);
      gl_lds16(pBL[j] + kk, &BsL[0][0][0] + c*4096 + ia*512);
    }
  };

  f32x4 acc[4][4];
  #pragma unroll
  for (int mi=0;mi<4;mi++)
    #pragma unroll
    for (int ni=0;ni<4;ni++) acc[mi][ni] = (f32x4){0.f,0.f,0.f,0.f};

  stage(0, 0);
  int cur = 0;
  for (int k0 = 0; k0 < K; k0 += 32){
    __syncthreads();                       // drains tile-k0 DMA (issued last iter / prologue)
    if (k0 + 32 < K) stage(cur ^ 1, k0 + 32);   // in flight across the MFMA block below
    f16x8 fah[4], fal[4], fbh[4], fbl[4];
    #pragma unroll
    for (int mi=0;mi<4;mi++){
      const int r = wm*64 + mi*16 + (lane&15), c = 8*(lane>>4);
      fah[mi] = __builtin_bit_cast(f16x8, *(const u32x4*)&AsH[cur][r][c]);
      fal[mi] = __builtin_bit_cast(f16x8, *(const u32x4*)&AsL[cur][r][c]);
    }
    #pragma unroll
    for (int ni=0;ni<4;ni++){
      const int r = wn*64 + ni*16 + (lane&15), c = 8*(lane>>4);
      fbh[ni] = __builtin_bit_cast(f16x8, *(const u32x4*)&BsH[cur][r][c]);
      fbl[ni] = __builtin_bit_cast(f16x8, *(const u32x4*)&BsL[cur][r][c]);
    }
    #pragma unroll
    for (int mi=0;mi<4;mi++)
      #pragma unroll
      for (int ni=0;ni<4;ni++){
        acc[mi][ni] = __builtin_amdgcn_mfma_f32_16x16x32_f16(fah[mi], fbh[ni], acc[mi][ni], 0, 0, 0);
        acc[mi][ni] = __builtin_amdgcn_mfma_f32_16x16x32_f16(fah[mi], fbl[ni], acc[mi][ni], 0, 0, 0);
        acc[mi][ni] = __builtin_amdgcn_mfma_f32_16x16x32_f16(fal[mi], fbh[ni], acc[mi][ni], 0, 0, 0);
      }
    cur ^= 1;
  }

  const float INV = 1.0f/1048576.0f;   // undo 1024*1024 scaling (exact pow2)
  const int erow = 4*(lane >> 4);
  const int ecol = lane & 15;
  #pragma unroll
  for (int mi=0;mi<4;mi++)
    #pragma unroll
    for (int ni=0;ni<4;ni++){
      const int c = col0 + wn*64 + ni*16 + ecol;
      const float bb = bp[c];
      #pragma unroll
      for (int r=0;r<4;r++){
        const int R = row0 + wm*64 + mi*16 + erow + r;
        const float v = acc[mi][ni][r]*INV + bb;
        if constexpr (OMODE == 0){
          C[(size_t)R*N + c] = v;
        } else if constexpr (OMODE == 1){
          C[(size_t)R*N + c] += cs*v;
        } else {
          const float vs = v * 1024.0f;
          const _Float16 hi = (_Float16)vs;
          Ch[(size_t)R*N + c] = hi;
          Cl[(size_t)R*N + c] = (_Float16)(vs - (float)hi);
        }
      }
    }
}

// ------- split-f16 MFMA attention (swapped-QK, in-register softmax) -------
__global__ __launch_bounds__(256,2) void attn_mfma_k(
    const _Float16* __restrict__ qkvH, const _Float16* __restrict__ qkvL,
    const float* __restrict__ mask,
    _Float16* __restrict__ ctxH, _Float16* __restrict__ ctxL)
{
  __shared__ _Float16 Kh[64][72], Kl[64][72];
  __shared__ _Float16 Vh[64][72], Vl[64][72];   // transposed: [d][k]
  __shared__ float msk[64];
  __shared__ float rsi[4][32];
  const int qb = blockIdx.x, h = blockIdx.y, b = blockIdx.z;
  const int tid = threadIdx.x;
  const int l = tid & 63, w = tid >> 6;
  const int l31 = l & 31, g5 = l >> 5;
  const float SC = 1.0f/8388608.0f;   // 2^-20 (split scale) * 1/8 (1/sqrt(64))

  u32x4 qfh[4], qfl[4];
  {
    const size_t qoff = (size_t)(b*Sq + qb*128 + w*32 + l31) * 2304 + h*DHq + g5*8;
    #pragma unroll
    for (int c = 0; c < 4; c++){
      qfh[c] = *(const u32x4*)(qkvH + qoff + c*16);
      qfl[c] = *(const u32x4*)(qkvL + qoff + c*16);
    }
  }
  f32x16 oacc[2];
  #pragma unroll
  for (int nt = 0; nt < 2; nt++)
    #pragma unroll
    for (int i = 0; i < 16; i++) oacc[nt][i] = 0.f;
  float rsl = 0.f;
  const float* mrow = mask + b*Sq;

  for (int kt = 0; kt < 8; kt++){
    __syncthreads();
    {
      const size_t krow = (size_t)(b*Sq + kt*64 + l) * 2304 + 768 + h*DHq;
      #pragma unroll
      for (int i = 0; i < 2; i++){
        const int ch = w + i*4;
        *(u32x4*)&Kh[l][ch*8] = *(const u32x4*)(qkvH + krow + ch*8);
        *(u32x4*)&Kl[l][ch*8] = *(const u32x4*)(qkvL + krow + ch*8);
      }
      const size_t vrow = krow + 768 + w*16;
      f16x8 v0 = __builtin_bit_cast(f16x8, *(const u32x4*)(qkvH + vrow));
      f16x8 v1 = __builtin_bit_cast(f16x8, *(const u32x4*)(qkvH + vrow + 8));
      f16x8 u0 = __builtin_bit_cast(f16x8, *(const u32x4*)(qkvL + vrow));
      f16x8 u1 = __builtin_bit_cast(f16x8, *(const u32x4*)(qkvL + vrow + 8));
      #pragma unroll
      for (int i = 0; i < 8; i++){
        Vh[w*16 + i][l] = v0[i]; Vh[w*16 + 8 + i][l] = v1[i];
        Vl[w*16 + i][l] = u0[i]; Vl[w*16 + 8 + i][l] = u1[i];
      }
      if (tid < 64) msk[tid] = mrow[kt*64 + tid] + 6.9314718055994531f; // + ln(1024)
    }
    __syncthreads();

    f32x16 sacc[2];
    #pragma unroll
    for (int mt = 0; mt < 2; mt++)
      #pragma unroll
      for (int i = 0; i < 16; i++) sacc[mt][i] = 0.f;
    #pragma unroll
    for (int mt = 0; mt < 2; mt++){
      #pragma unroll
      for (int c = 0; c < 4; c++){
        f16x8 kh = __builtin_bit_cast(f16x8, *(const u32x4*)&Kh[mt*32 + l31][c*16 + g5*8]);
        f16x8 kl = __builtin_bit_cast(f16x8, *(const u32x4*)&Kl[mt*32 + l31][c*16 + g5*8]);
        f16x8 qh = __builtin_bit_cast(f16x8, qfh[c]);
        f16x8 ql = __builtin_bit_cast(f16x8, qfl[c]);
        sacc[mt] = __builtin_amdgcn_mfma_f32_32x32x16_f16(kh, qh, sacc[mt], 0, 0, 0);
        sacc[mt] = __builtin_amdgcn_mfma_f32_32x32x16_f16(kh, ql, sacc[mt], 0, 0, 0);
        sacc[mt] = __builtin_amdgcn_mfma_f32_32x32x16_f16(kl, qh, sacc[mt], 0, 0, 0);
      }
    }

    unsigned int hP[2][4][2], lP[2][4][2];
    #pragma unroll
    for (int mt = 0; mt < 2; mt++){
      #pragma unroll
      for (int m = 0; m < 4; m++){
        f32x4 mk = *(const f32x4*)&msk[mt*32 + m*8 + g5*4];
        float p0 = __expf(fmaf(sacc[mt][4*m+0], SC, mk[0]));
        float p1 = __expf(fmaf(sacc[mt][4*m+1], SC, mk[1]));
        float p2 = __expf(fmaf(sacc[mt][4*m+2], SC, mk[2]));
        float p3 = __expf(fmaf(sacc[mt][4*m+3], SC, mk[3]));
        rsl += (p0 + p1) + (p2 + p3);
        f16x2 h0 = cvt_pk(p0, p1);
        f16x2 h1 = cvt_pk(p2, p3);
        f16x2 e0, e1;
        e0[0] = (_Float16)(p0 - (float)h0[0]); e0[1] = (_Float16)(p1 - (float)h0[1]);
        e1[0] = (_Float16)(p2 - (float)h1[0]); e1[1] = (_Float16)(p3 - (float)h1[1]);
        hP[mt][m][0] = __builtin_bit_cast(unsigned int, h0);
        hP[mt][m][1] = __builtin_bit_cast(unsigned int, h1);
        lP[mt][m][0] = __builtin_bit_cast(unsigned int, e0);
        lP[mt][m][1] = __builtin_bit_cast(unsigned int, e1);
      }
    }

    #pragma unroll
    for (int mt = 0; mt < 2; mt++){
      #pragma unroll
      for (int cc = 0; cc < 2; cc++){
        i32x2 sh0 = pl32swap(hP[mt][2*cc][0], hP[mt][2*cc+1][0]);
        i32x2 sh1 = pl32swap(hP[mt][2*cc][1], hP[mt][2*cc+1][1]);
        i32x2 sl0 = pl32swap(lP[mt][2*cc][0], lP[mt][2*cc+1][0]);
        i32x2 sl1 = pl32swap(lP[mt][2*cc][1], lP[mt][2*cc+1][1]);
        u32x4 pah = (u32x4){(unsigned)sh0[0], (unsigned)sh1[0], (unsigned)sh0[1], (unsigned)sh1[1]};
        u32x4 pal = (u32x4){(unsigned)sl0[0], (unsigned)sl1[0], (unsigned)sl0[1], (unsigned)sl1[1]};
        f16x8 ph = __builtin_bit_cast(f16x8, pah);
        f16x8 pe = __builtin_bit_cast(f16x8, pal);
        const int kof = (mt*2 + cc)*16 + g5*8;
        #pragma unroll
        for (int nt = 0; nt < 2; nt++){
          f16x8 vh = __builtin_bit_cast(f16x8, *(const u32x4*)&Vh[nt*32 + l31][kof]);
          f16x8 vl = __builtin_bit_cast(f16x8, *(const u32x4*)&Vl[nt*32 + l31][kof]);
          oacc[nt] = __builtin_amdgcn_mfma_f32_32x32x16_f16(ph, vh, oacc[nt], 0, 0, 0);
          oacc[nt] = __builtin_amdgcn_mfma_f32_32x32x16_f16(ph, vl, oacc[nt], 0, 0, 0);
          oacc[nt] = __builtin_amdgcn_mfma_f32_32x32x16_f16(pe, vh, oacc[nt], 0, 0, 0);
        }
      }
    }
  }

  {
    unsigned int rb = __builtin_bit_cast(unsigned int, rsl);
    i32x2 sw = pl32swap(rb, rb);
    float partner = __builtin_bit_cast(float, (l >= 32) ? sw[0] : sw[1]);
    float tot = rsl + partner;
    if (l < 32) rsi[w][l31] = 1.0f / tot;
  }
  __syncthreads();

  const size_t obase = (size_t)(b*Sq + qb*128 + w*32);
  #pragma unroll
  for (int nt = 0; nt < 2; nt++){
    const int col = h*DHq + nt*32 + l31;
    #pragma unroll
    for (int r = 0; r < 16; r++){
      const int q = (r&3) + 8*(r>>2) + 4*g5;
      const float v = oacc[nt][r] * rsi[w][q];
      const _Float16 hi = (_Float16)v;
      const size_t off = (obase + q)*Dq + col;
      ctxH[off] = hi;
      ctxL[off] = (_Float16)(v - (float)hi);
    }
  }
}

// ---------------- transpose + f32->bf16 (FFN weights -> [N][K] bf16) ----------------
__global__ void transpose_bf16_k(const float* __restrict__ src, unsigned short* __restrict__ dst,
                                 int K, int N)
{
  __shared__ float t[64][65];
  const int tid = threadIdx.x;
  const size_t mo = (size_t)blockIdx.z * K * N;
  const int k0 = blockIdx.y * 64, n0 = blockIdx.x * 64;
  const int r = tid >> 2, c0 = (tid & 3) * 16;
  const float* sp = src + mo + (size_t)(k0 + r) * N + n0 + c0;
  #pragma unroll
  for (int cc = 0; cc < 16; cc += 4){
    f32x4 v = *(const f32x4*)(sp + cc);
    t[r][c0+cc] = v[0]; t[r][c0+cc+1] = v[1]; t[r][c0+cc+2] = v[2]; t[r][c0+cc+3] = v[3];
  }
  __syncthreads();
  unsigned short* dp = dst + mo + (size_t)(n0 + r) * K + k0 + c0;
  u32x4 h0, h1v;
  #pragma unroll
  for (int i = 0; i < 4; i++) h0[i]  = pk2(t[c0+2*i  ][r], t[c0+2*i+1][r]);
  #pragma unroll
  for (int i = 0; i < 4; i++) h1v[i] = pk2(t[c0+8+2*i][r], t[c0+9+2*i][r]);
  *(u32x4*)(dp)     = h0;
  *(u32x4*)(dp + 8) = h1v;
}

// ------- bf16 MFMA GEMM (FFN path), double-buffered staging -------
// MT: 128 or 64 row tile. AMODE: 0 f32 rows reg-staged; 1 f32 rows via tok_idx; 2 bf16 DMA
// OMODE: 0 bf16 store; 1 f32 write+bias; 2 f32 scatter add gate*(res+bias)
template<int MT, int AMODE, int OMODE, bool GELU_, bool GROUPED>
__global__ __launch_bounds__(256,2) void gemm_bf16_k(
    const void* __restrict__ Av, const unsigned short* __restrict__ BT,
    const float* __restrict__ bias, float* __restrict__ Cf, unsigned short* __restrict__ Cb,
    int N, int K,
    const int* __restrict__ tile_g, const int* __restrict__ tile_r0,
    const int* __restrict__ grp_off, const int* __restrict__ n_tiles,
    const int* __restrict__ tok_idx, const float* __restrict__ gate_s,
    size_t bstride, int bias_stride)
{
  constexpr int MI = MT / 32;            // acc rows per wave
  constexpr int AI = MT / 64;            // A DMA instrs per wave (AMODE==2)
  __shared__ unsigned short As[2][MT][32];
  __shared__ unsigned short Bs[2][128][32];
  const int tid = threadIdx.x;
  const int lane = tid & 63, wave = tid >> 6;
  const int wm = wave >> 1, wn = wave & 1;
  int col0, row0, gend = 1 << 30, g = 0;
  if constexpr (GROUPED){
    const int gx = gridDim.x;
    const int nb = gx * gridDim.y;
    const int bid = blockIdx.y * gx + blockIdx.x;
    int lb = bid;
    if ((nb & 7) == 0) lb = (bid & 7) * (nb >> 3) + (bid >> 3);
    const int t = lb / gx;
    col0 = (lb - t * gx) * 128;
    if (t >= *n_tiles) return;
    g = tile_g[t];
    row0 = grp_off[g] + tile_r0[t];
    gend = grp_off[g+1];
  } else {
    int bx, by; swz2d(bx, by);
    row0 = by * MT;
    col0 = bx * 128;
  }
  const unsigned short* Bp = BT + (size_t)g * bstride;
  const float* bp = bias + (size_t)g * bias_stride;

  const int lr = lane >> 2, lk8 = (lane & 3) * 8;
  // B staging: always DMA (2 x 1KB per wave)
  const unsigned short* pB[2];
  #pragma unroll
  for (int j = 0; j < 2; j++){
    const int ib = wave*2 + j;
    pB[j] = Bp + (size_t)(col0 + ib*16 + lr)*K + lk8;
  }
  auto stageB = [&](int c, int kk){
    gl_lds16(pB[0] + kk, &Bs[0][0][0] + c*4096 + (wave*2+0)*512);
    gl_lds16(pB[1] + kk, &Bs[0][0][0] + c*4096 + (wave*2+1)*512);
  };
  // A staging
  const unsigned short* pA2[AI];
  const float* afp = nullptr; int sa_r = 0, sa_k = 0;
  if constexpr (AMODE == 2){
    #pragma unroll
    for (int j = 0; j < AI; j++){
      int r = row0 + (wave*AI + j)*16 + lr;
      if constexpr (GROUPED) r = (r < gend - 1) ? r : (gend - 1);
      pA2[j] = (const unsigned short*)Av + (size_t)r*K + lk8;
    }
  } else {
    sa_r = (MT == 128) ? (tid >> 1) : (tid >> 2);
    sa_k = (MT == 128) ? ((tid & 1) * 16) : ((tid & 3) * 8);
    int arow = row0 + sa_r;
    if constexpr (GROUPED) arow = (arow < gend - 1) ? arow : (gend - 1);
    if constexpr (AMODE == 1) arow = tok_idx[arow];
    afp = (const float*)Av + (size_t)arow * K + sa_k;
  }
  auto stageA2 = [&](int c, int kk){
    #pragma unroll
    for (int j = 0; j < AI; j++)
      gl_lds16(pA2[j] + kk, &As[0][0][0] + c*(MT*32) + (wave*AI + j)*512);
  };

  f32x4 acc[MI][4];
  #pragma unroll
  for (int mi=0;mi<MI;mi++)
    #pragma unroll
    for (int ni=0;ni<4;ni++) acc[mi][ni] = (f32x4){0.f,0.f,0.f,0.f};

  const int nt = K >> 5;
  // ---- prologue: stage tile 0 into buffer 0 ----
  if constexpr (AMODE == 2){
    stageA2(0, 0);
  } else {
    f32x4 f0 = *(const f32x4*)(afp);
    f32x4 f1 = *(const f32x4*)(afp + 4);
    u32x4 al0;
    al0[0]=pk2(f0[0],f0[1]); al0[1]=pk2(f0[2],f0[3]); al0[2]=pk2(f1[0],f1[1]); al0[3]=pk2(f1[2],f1[3]);
    *(u32x4*)&As[0][sa_r][sa_k] = al0;
    if constexpr (MT == 128){
      f32x4 f2 = *(const f32x4*)(afp + 8);
      f32x4 f3 = *(const f32x4*)(afp + 12);
      u32x4 al1;
      al1[0]=pk2(f2[0],f2[1]); al1[1]=pk2(f2[2],f2[3]); al1[2]=pk2(f3[0],f3[1]); al1[3]=pk2(f3[2],f3[3]);
      *(u32x4*)&As[0][sa_r][sa_k + 8] = al1;
    }
  }
  stageB(0, 0);

  int cur = 0;
  for (int t = 0; t < nt; t++){
    __syncthreads();                      // tile t ready (DMA drained, ds_writes visible)
    const int k1 = (t + 1) << 5;
    f32x4 f0n, f1n, f2n, f3n;
    const bool nxt = (t + 1 < nt);
    if (nxt){
      if constexpr (AMODE == 2){
        stageA2(cur ^ 1, k1);
      } else {
        f0n = *(const f32x4*)(afp + k1);
        f1n = *(const f32x4*)(afp + k1 + 4);
        if constexpr (MT == 128){
          f2n = *(const f32x4*)(afp + k1 + 8);
          f3n = *(const f32x4*)(afp + k1 + 12);
        }
      }
      stageB(cur ^ 1, k1);
    }
    bf16x8 af[MI], bfr[4];
    #pragma unroll
    for (int mi=0;mi<MI;mi++){
      u32x4 tt = *(const u32x4*)&As[cur][wm*(MT/2) + mi*16 + (lane&15)][8*(lane>>4)];
      af[mi] = __builtin_bit_cast(bf16x8, tt);
    }
    #pragma unroll
    for (int ni=0;ni<4;ni++){
      u32x4 tt = *(const u32x4*)&Bs[cur][wn*64 + ni*16 + (lane&15)][8*(lane>>4)];
      bfr[ni] = __builtin_bit_cast(bf16x8, tt);
    }
    #pragma unroll
    for (int mi=0;mi<MI;mi++)
      #pragma unroll
      for (int ni=0;ni<4;ni++)
        acc[mi][ni] = __builtin_amdgcn_mfma_f32_16x16x32_bf16(af[mi], bfr[ni], acc[mi][ni], 0, 0, 0);
    if (nxt){
      if constexpr (AMODE != 2){
        u32x4 al0;
        al0[0]=pk2(f0n[0],f0n[1]); al0[1]=pk2(f0n[2],f0n[3]); al0[2]=pk2(f1n[0],f1n[1]); al0[3]=pk2(f1n[2],f1n[3]);
        *(u32x4*)&As[cur^1][sa_r][sa_k] = al0;
        if constexpr (MT == 128){
          u32x4 al1;
          al1[0]=pk2(f2n[0],f2n[1]); al1[1]=pk2(f2n[2],f2n[3]); al1[2]=pk2(f3n[0],f3n[1]); al1[3]=pk2(f3n[2],f3n[3]);
          *(u32x4*)&As[cur^1][sa_r][sa_k + 8] = al1;
        }
      }
    }
    cur ^= 1;
  }

  const int erow = 4*(lane >> 4);
  const int ecol = lane & 15;
  #pragma unroll
  for (int mi=0;mi<MI;mi++)
    #pragma unroll
    for (int ni=0;ni<4;ni++){
      const int c = col0 + wn*64 + ni*16 + ecol;
      const float bb = bp[c];
      #pragma unroll
      for (int r=0;r<4;r++){
        const int R = row0 + wm*(MT/2) + mi*16 + erow + r;
        if (GROUPED && R >= gend) continue;
        float v = acc[mi][ni][r] + bb;
        if (GELU_) v = 0.5f*v*(1.0f + erff(v*0.70710678118654752f));
        if constexpr (OMODE == 0){
          Cb[(size_t)R*N + c] = f2bf(v);
        } else if constexpr (OMODE == 1){
          Cf[(size_t)R*N + c] = v;
        } else {
          const int tok = tok_idx[R];
          const float gt = gate_s[R];
          float* p = Cf + (size_t)tok*N + c;
          *p += gt*v;
        }
      }
    }
}

// ---------------- token-level switch router (f32, one wave/token) ----------------
__global__ void token_router_k(const float* __restrict__ att, const int* __restrict__ sel,
    const float* __restrict__ sww, const float* __restrict__ swb,
    int* __restrict__ grp, float* __restrict__ gate, int* __restrict__ grp_cnt)
{
  const int t = blockIdx.x*4 + (threadIdx.x >> 6);
  const int lane = threadIdx.x & 63;
  const int e = sel[t >> 9];
  const float* x = att + (size_t)t * Dq;
  const float* w = sww + (size_t)e * Dq * 4;
  float a0=0.f, a1=0.f, a2=0.f, a3=0.f;
  #pragma unroll 4
  for (int i = 0; i < 12; i++){
    const int d = lane + i*64;
    const float xv = x[d];
    f32x4 wv = *(const f32x4*)&w[d*4];
    a0 += xv*wv[0]; a1 += xv*wv[1]; a2 += xv*wv[2]; a3 += xv*wv[3];
  }
  #pragma unroll
  for (int off = 32; off; off >>= 1){
    a0 += __shfl_xor(a0, off); a1 += __shfl_xor(a1, off);
    a2 += __shfl_xor(a2, off); a3 += __shfl_xor(a3, off);
  }
  if (lane == 0){
    const float l0 = a0 + swb[e*4+0], l1 = a1 + swb[e*4+1];
    const float l2 = a2 + swb[e*4+2], l3 = a3 + swb[e*4+3];
    const float mx = fmaxf(fmaxf(l0,l1), fmaxf(l2,l3));
    const float p0 = expf(l0-mx), p1 = expf(l1-mx), p2 = expf(l2-mx), p3 = expf(l3-mx);
    const float ssum = p0+p1+p2+p3;
    int am = 0; float bv = p0;
    if (p1 > bv){ bv=p1; am=1; }
    if (p2 > bv){ bv=p2; am=2; }
    if (p3 > bv){ bv=p3; am=3; }
    grp[t] = e*4 + am;
    gate[t] = bv/ssum;
    atomicAdd(&grp_cnt[e*4 + am], 1);
  }
}

__global__ void build_offsets_k(const int* __restrict__ grp_cnt, int* __restrict__ grp_off,
    int* __restrict__ tg128, int* __restrict__ tr128, int* __restrict__ nt128,
    int* __restrict__ tg64, int* __restrict__ tr64, int* __restrict__ nt64)
{
  int off = 0, n1 = 0, n2 = 0;
  for (int g = 0; g < 16; g++){
    grp_off[g] = off;
    const int c = grp_cnt[g];
    for (int r0 = 0; r0 < c; r0 += 128){ tg128[n1] = g; tr128[n1] = r0; n1++; }
    for (int r0 = 0; r0 < c; r0 += 64){  tg64[n2]  = g; tr64[n2]  = r0; n2++; }
    off += c;
  }
  grp_off[16] = off;
  *nt128 = n1; *nt64 = n2;
}

__global__ void scatter_k(const int* __restrict__ grp, const float* __restrict__ gate,
    const int* __restrict__ grp_off, int* __restrict__ fill,
    int* __restrict__ tok_idx, float* __restrict__ gate_s)
{
  const int t = blockIdx.x*256 + threadIdx.x;
  const int g = grp[t];
  const int pos = grp_off[g] + atomicAdd(&fill[g], 1);
  tok_idx[pos] = t;
  gate_s[pos] = gate[t];
}

// ---------------- final residual-add + LayerNorm ----------------
__global__ __launch_bounds__(256) void final_ln_k(const float* __restrict__ att,
    const float* __restrict__ acc, const float* __restrict__ lg,
    const float* __restrict__ lb, float* __restrict__ out)
{
  const int row = blockIdx.x, tid = threadIdx.x;
  const float* a = att + (size_t)row * Dq;
  const float* c = acc + (size_t)row * Dq;
  float x[3];
  #pragma unroll
  for (int i = 0; i < 3; i++) x[i] = a[tid + 256*i] + c[tid + 256*i];
  __shared__ float red[256];
  red[tid] = x[0] + x[1] + x[2];
  __syncthreads();
  for (int st = 128; st; st >>= 1){
    if (tid < st) red[tid] += red[tid + st];
    __syncthreads();
  }
  const float mu = red[0] * (1.0f/768.0f);
  __syncthreads();
  const float d0 = x[0]-mu, d1 = x[1]-mu, d2 = x[2]-mu;
  red[tid] = d0*d0 + d1*d1 + d2*d2;
  __syncthreads();
  for (int st = 128; st; st >>= 1){
    if (tid < st) red[tid] += red[tid + st];
    __syncthreads();
  }
  const float inv = 1.0f/sqrtf(red[0]*(1.0f/768.0f) + 1e-12f);
  #pragma unroll
  for (int i = 0; i < 3; i++){
    const int col = tid + 256*i;
    out[(size_t)row*Dq + col] = (x[i]-mu)*inv*lg[col] + lb[col];
  }
}

// ======================= launch =======================
extern "C" void kernel_launch(void* const* d_in, const int* in_sizes, int n_in,
                              void* d_out, int out_size, void* d_ws, size_t ws_size,
                              hipStream_t stream)
{
  (void)in_sizes; (void)n_in; (void)out_size; (void)ws_size;
  const float* hs    = (const float*)d_in[0];
  const float* amask = (const float*)d_in[1];
  const float* sw_enc_w = (const float*)d_in[3];
  const float* sw_enc_b = (const float*)d_in[4];
  const float* sw_w  = (const float*)d_in[5];
  const float* sw_b  = (const float*)d_in[6];
  const float* ca_wq = (const float*)d_in[7];
  const float* ca_bq = (const float*)d_in[8];
  const float* ca_wk = (const float*)d_in[9];
  const float* ca_bk = (const float*)d_in[10];
  const float* ca_wv = (const float*)d_in[11];
  const float* ca_bv = (const float*)d_in[12];
  const float* ca_wo = (const float*)d_in[13];
  const float* ca_bo = (const float*)d_in[14];
  const float* ua_wq = (const float*)d_in[15];
  const float* ua_bq = (const float*)d_in[16];
  const float* ua_wk = (const float*)d_in[17];
  const float* ua_bk = (const float*)d_in[18];
  const float* ua_wv = (const float*)d_in[19];
  const float* ua_bv = (const float*)d_in[20];
  const float* ua_wo = (const float*)d_in[21];
  const float* ua_bo = (const float*)d_in[22];
  const float* cf_w1 = (const float*)d_in[23];
  const float* cf_b1 = (const float*)d_in[24];
  const float* cf_w2 = (const float*)d_in[25];
  const float* cf_b2 = (const float*)d_in[26];
  const float* uf_sw_w = (const float*)d_in[27];
  const float* uf_sw_b = (const float*)d_in[28];
  const float* uf_w1 = (const float*)d_in[29];
  const float* uf_b1 = (const float*)d_in[30];
  const float* uf_w2 = (const float*)d_in[31];
  const float* uf_b2 = (const float*)d_in[32];
  const float* ln_g  = (const float*)d_in[33];
  const float* ln_b  = (const float*)d_in[34];
  float* out = (float*)d_out;

  char* W = (char*)d_ws;
  // control block
  int*   sel     = (int*)(W + 0);
  float* pm      = (float*)(W + 64);
  int*   grp_cnt = (int*)(W + 128);
  int*   fill    = (int*)(W + 192);
  int*   ntile   = (int*)(W + 256);
  int*   ntile64 = (int*)(W + 320);
  int*   grp_off = (int*)(W + 512);
  int*   tile_g  = (int*)(W + 1024);
  int*   tile_r  = (int*)(W + 2048);
  int*   tile_g64= (int*)(W + 3072);
  int*   tile_r64= (int*)(W + 4096);

  float* att  = (float*)(W + 8192);             // [8192][768] f32
  float* facc = (float*)(W + 25174016);         // [8192][768] f32
  const size_t X = 50339840;
  _Float16* hsH  = (_Float16*)(W + X);                 // 12,582,912
  _Float16* hsL  = (_Float16*)(W + X + 12582912);
  _Float16* qkvH = (_Float16*)(W + X + 25165824);      // 37,748,736
  _Float16* qkvL = (_Float16*)(W + X + 62914560);      // end X+100663296
  _Float16* ctxH = (_Float16*)(W + X + 100663296);     // 12,582,912
  _Float16* ctxL = (_Float16*)(W + X + 113246208);     // end X+125829120
  _Float16* wqkv_cH = (_Float16*)(W + X + 125829120);  // 3,538,944
  _Float16* wqkv_cL = (_Float16*)(W + X + 129368064);
  _Float16* wqkv_uH = (_Float16*)(W + X + 132907008);  // 14,155,776
  _Float16* wqkv_uL = (_Float16*)(W + X + 147062784);
  _Float16* wo_cH   = (_Float16*)(W + X + 161218560);  // 1,179,648
  _Float16* wo_cL   = (_Float16*)(W + X + 162398208);
  _Float16* wo_uH   = (_Float16*)(W + X + 163577856);  // 4,718,592
  _Float16* wo_uL   = (_Float16*)(W + X + 168296448);  // end X+173015040
  float* qkvb_c = (float*)(W + X + 173015040);         // 9,216
  float* qkvb_u = (float*)(W + X + 173024256);         // 36,864
  float* partb  = (float*)(W + X + 173061120);         // 196,608

  // phase B (after attention) reuses phase-A scratch:
  unsigned short* w1T = (unsigned short*)(W + X);              // 80,216,064
  unsigned short* w2T = (unsigned short*)(W + X + 80216064);   // end X+160432128
  unsigned short* h1  = (unsigned short*)(W + X + 160432128);  // 50,331,648
  int*   grp     = (int*)(W + 261103616);
  float* gate    = (float*)(W + 261136384);
  int*   tok_idx = (int*)(W + 261169152);
  float* gate_s  = (float*)(W + 261201920);

  hipMemsetAsync(W, 0, 512, stream);

  // ---- sequence router (exact f32) ----
  pooled_partial_k<<<dim3(Bq,3,4),256,0,stream>>>(hs, partb);
  router_seq_k<<<Bq,128,0,stream>>>(partb, sw_enc_w, sw_enc_b, sw_w, sw_b, sel, pm);

  // ---- prepare split-f16 operands ----
  split_f16_k<<<6144,256,0,stream>>>(hs, hsH, hsL, NTq*Dq/4);
  transpose_f16s_k<<<dim3(12,12,1),256,0,stream>>>(ca_wq, wqkv_cH, wqkv_cL, Dq, Dq, 0, 0, 0);
  transpose_f16s_k<<<dim3(12,12,1),256,0,stream>>>(ca_wk, wqkv_cH, wqkv_cL, Dq, Dq, 0, 0, 768);
  transpose_f16s_k<<<dim3(12,12,1),256,0,stream>>>(ca_wv, wqkv_cH, wqkv_cL, Dq, Dq, 0, 0, 1536);
  transpose_f16s_k<<<dim3(12,12,4),256,0,stream>>>(ua_wq, wqkv_uH, wqkv_uL, Dq, Dq, (long)Dq*Dq, (long)2304*768, 0);
  transpose_f16s_k<<<dim3(12,12,4),256,0,stream>>>(ua_wk, wqkv_uH, wqkv_uL, Dq, Dq, (long)Dq*Dq, (long)2304*768, 768);
  transpose_f16s_k<<<dim3(12,12,4),256,0,stream>>>(ua_wv, wqkv_uH, wqkv_uL, Dq, Dq, (long)Dq*Dq, (long)2304*768, 1536);
  transpose_f16s_k<<<dim3(12,12,1),256,0,stream>>>(ca_wo, wo_cH, wo_cL, Dq, Dq, 0, 0, 0);
  transpose_f16s_k<<<dim3(12,12,4),256,0,stream>>>(ua_wo, wo_uH, wo_uL, Dq, Dq, (long)Dq*Dq, (long)Dq*Dq, 0);
  concat_bias3_k<<<dim3(3,1),256,0,stream>>>(ca_bq, ca_bk, ca_bv, qkvb_c, 0);
  concat_bias3_k<<<dim3(3,4),256,0,stream>>>(ua_bq, ua_bk, ua_bv, qkvb_u, 768);

  // ---- common attention ----
  gemm_f16s_k<0,2><<<dim3(18,64),256,0,stream>>>(hsH, hsL, wqkv_cH, wqkv_cL, qkvb_c,
      nullptr, qkvH, qkvL, 2304, Dq, 0, 0, nullptr, nullptr);
  attn_mfma_k<<<dim3(4,Hq,Bq),256,0,stream>>>(qkvH, qkvL, amask, ctxH, ctxL);
  gemm_f16s_k<0,0><<<dim3(6,64),256,0,stream>>>(ctxH, ctxL, wo_cH, wo_cL, ca_bo,
      att, nullptr, nullptr, Dq, Dq, 0, 0, nullptr, nullptr);

  // ---- unique attention (selected expert), att += pm * result ----
  gemm_f16s_k<1,2><<<dim3(18,64),256,0,stream>>>(hsH, hsL, wqkv_uH, wqkv_uL, qkvb_u,
      nullptr, qkvH, qkvL, 2304, Dq, (long)2304*768, 2304, sel, nullptr);
  attn_mfma_k<<<dim3(4,Hq,Bq),256,0,stream>>>(qkvH, qkvL, amask, ctxH, ctxL);
  gemm_f16s_k<1,1><<<dim3(6,64),256,0,stream>>>(ctxH, ctxL, wo_uH, wo_uL, ua_bo,
      att, nullptr, nullptr, Dq, Dq, (long)Dq*Dq, Dq, sel, pm);

  // ---- FFN weights -> transposed bf16 (phase-A scratch now free) ----
  transpose_bf16_k<<<dim3(48,12,1), 256,0,stream>>>(cf_w1, w1T, Dq, Fq);
  transpose_bf16_k<<<dim3(48,12,16),256,0,stream>>>(uf_w1, w1T + 2359296, Dq, Fq);
  transpose_bf16_k<<<dim3(12,48,1), 256,0,stream>>>(cf_w2, w2T, Fq, Dq);
  transpose_bf16_k<<<dim3(12,48,16),256,0,stream>>>(uf_w2, w2T + 2359296, Fq, Dq);

  // ---- common FFN (bf16 MFMA) ----
  gemm_bf16_k<128,0,0,true,false><<<dim3(24,64),256,0,stream>>>((const void*)att, w1T, cf_b1, nullptr, h1,
      Fq, Dq, nullptr,nullptr,nullptr,nullptr,nullptr,nullptr, (size_t)0, 0);
  gemm_bf16_k<64,2,1,false,false><<<dim3(6,128),256,0,stream>>>((const void*)h1, w2T, cf_b2, facc, nullptr,
      Dq, Fq, nullptr,nullptr,nullptr,nullptr,nullptr,nullptr, (size_t)0, 0);

  // ---- token routing (f32, on accurate att) ----
  token_router_k<<<2048,256,0,stream>>>(att, sel, uf_sw_w, uf_sw_b, grp, gate, grp_cnt);
  build_offsets_k<<<1,1,0,stream>>>(grp_cnt, grp_off, tile_g, tile_r, ntile, tile_g64, tile_r64, ntile64);
  scatter_k<<<32,256,0,stream>>>(grp, gate, grp_off, fill, tok_idx, gate_s);

  // ---- unique FFN (grouped, top-1 inner expert, gated scatter-add) ----
  gemm_bf16_k<128,1,0,true,true><<<dim3(24,80),256,0,stream>>>((const void*)att, w1T + 2359296, uf_b1, nullptr, h1,
      Fq, Dq, tile_g, tile_r, grp_off, ntile, tok_idx, gate_s, (size_t)2359296, Fq);
  gemm_bf16_k<64,2,2,false,true><<<dim3(6,144),256,0,stream>>>((const void*)h1, w2T + 2359296, uf_b2, facc, nullptr,
      Dq, Fq, tile_g64, tile_r64, grp_off, ntile64, tok_idx, gate_s, (size_t)2359296, Dq);

  // ---- residual + LayerNorm ----
  final_ln_k<<<NTq,256,0,stream>>>(att, facc, ln_g, ln_b, out);
}

// Round 9
// 1148.164 us; speedup vs baseline: 1.0226x; 1.0226x over previous
//
#include <hip/hip_runtime.h>
#include <cstdint>
#include <cstddef>

#define Bq  16
#define Sq  512
#define Dq  768
#define Hq  12
#define DHq 64
#define Fq  3072
#define SWq 128
#define NTq 8192

typedef float        f32x4  __attribute__((ext_vector_type(4)));
typedef float        f32x16 __attribute__((ext_vector_type(16)));
typedef unsigned int u32x4  __attribute__((ext_vector_type(4)));
typedef __bf16       bf16x8 __attribute__((ext_vector_type(8)));
typedef _Float16     f16x8  __attribute__((ext_vector_type(8)));
typedef _Float16     f16x4  __attribute__((ext_vector_type(4)));
typedef _Float16     f16x2  __attribute__((ext_vector_type(2)));
typedef int          i32x2  __attribute__((ext_vector_type(2)));

__device__ __forceinline__ unsigned short f2bf(float f){
  unsigned int u = __builtin_bit_cast(unsigned int, f);
  u = (u + 0x7fffu + ((u >> 16) & 1u)) >> 16;
  return (unsigned short)u;
}
__device__ __forceinline__ unsigned int pk2(float a, float b){
  return (unsigned int)f2bf(a) | ((unsigned int)f2bf(b) << 16);
}
__device__ __forceinline__ i32x2 pl32swap(unsigned int a, unsigned int b){
  return __builtin_amdgcn_permlane32_swap((int)a, (int)b, false, false);
}
__device__ __forceinline__ f16x2 cvt_pk(float a, float b){
  return __builtin_bit_cast(f16x2, __builtin_amdgcn_cvt_pkrtz(a, b));
}

// async global->LDS DMA, 16B per lane. LDS dest = wave-uniform base + lane*16.
typedef __attribute__((address_space(1))) void vg_t;
typedef __attribute__((address_space(3))) void vl_t;
__device__ __forceinline__ void gl_lds16(const void* g, void* l){
  __builtin_amdgcn_global_load_lds((vg_t*)g, (vl_t*)l, 16, 0, 0);
}

// Band-supertile + XCD-aware bijective block remap (non-grouped GEMMs).
__device__ __forceinline__ void swz2d(int &bx, int &by){
  const int gx = gridDim.x, gy = gridDim.y;
  const int nb = gx * gy;
  const int bid = blockIdx.y * gx + blockIdx.x;
  if (((nb & 7) == 0) && ((gy & 7) == 0)){
    const int chunk = nb >> 3;
    const int lb = (bid & 7) * chunk + (bid >> 3);
    const int bw = gx << 3;              // blocks per band
    const int band = lb / bw;
    const int wn = lb - band * bw;
    bx = wn >> 3;
    by = (band << 3) + (wn & 7);
  } else {
    bx = blockIdx.x; by = blockIdx.y;
  }
}

// ---------------- pooled partial sums (seq router input) ----------------
__global__ void pooled_partial_k(const float* __restrict__ x, float* __restrict__ part){
  const int b = blockIdx.x, dc = blockIdx.y, z = blockIdx.z;
  const int d = dc*256 + threadIdx.x;
  const float* p = x + (size_t)b*Sq*Dq + (size_t)z*128*Dq + d;
  float s = 0.f;
  #pragma unroll 4
  for (int i = 0; i < 128; i++) s += p[(size_t)i*Dq];
  part[((size_t)z*Bq + b)*Dq + d] = s;
}

// ---------------- sequence-level router (exact f32) ----------------
__global__ void router_seq_k(const float* __restrict__ part,
    const float* __restrict__ ew, const float* __restrict__ eb,
    const float* __restrict__ sw, const float* __restrict__ sb,
    int* __restrict__ sel, float* __restrict__ pm)
{
  const int b = blockIdx.x, j = threadIdx.x;   // 128 threads
  __shared__ float h[SWq];
  __shared__ float pl[Dq];
  #pragma unroll
  for (int i = 0; i < 6; i++){
    int d = j + i*128;
    float s = part[(size_t)(0*Bq+b)*Dq + d] + part[(size_t)(1*Bq+b)*Dq + d]
            + part[(size_t)(2*Bq+b)*Dq + d] + part[(size_t)(3*Bq+b)*Dq + d];
    pl[d] = s * (1.0f/512.0f);
  }
  __syncthreads();
  float a = eb[j];
  for (int d = 0; d < Dq; d++) a += pl[d] * ew[d*SWq + j];
  h[j] = a;
  __syncthreads();
  if (j == 0){
    float lg[4];
    for (int e = 0; e < 4; e++){
      float t = sb[e];
      for (int k = 0; k < SWq; k++) t += h[k] * sw[k*4 + e];
      lg[e] = t;
    }
    float mx = fmaxf(fmaxf(lg[0],lg[1]), fmaxf(lg[2],lg[3]));
    float p[4], ssum = 0.f;
    for (int e = 0; e < 4; e++){ p[e] = expf(lg[e]-mx); ssum += p[e]; }
    int am = 0; float bv = p[0];
    for (int e = 1; e < 4; e++) if (p[e] > bv){ bv = p[e]; am = e; }
    sel[b] = am; pm[b] = bv/ssum;
  }
}

// ---------------- f32 -> f16 hi/lo split (x1024 scale) ----------------
__global__ void split_f16_k(const float* __restrict__ x, _Float16* __restrict__ hh,
                            _Float16* __restrict__ ll, int n4){
  const int i = blockIdx.x*256 + threadIdx.x;
  if (i >= n4) return;
  f32x4 v = ((const f32x4*)x)[i];
  f16x4 vh, vl;
  #pragma unroll
  for (int j = 0; j < 4; j++){
    float s = v[j] * 1024.0f;
    _Float16 a = (_Float16)s;
    vh[j] = a;
    vl[j] = (_Float16)(s - (float)a);
  }
  ((f16x4*)hh)[i] = vh;
  ((f16x4*)ll)[i] = vl;
}

// ------- weight transpose + f16 hi/lo split: src [K][N] -> dst [N][K] x1024 -------
__global__ void transpose_f16s_k(const float* __restrict__ src,
    _Float16* __restrict__ dH, _Float16* __restrict__ dL,
    int K, int N, long srcStride, long dstStride, int rowOff)
{
  __shared__ float t[64][65];
  const int tid = threadIdx.x;
  const size_t so = (size_t)blockIdx.z * srcStride;
  const size_t dof = (size_t)blockIdx.z * dstStride;
  const int k0 = blockIdx.y * 64, n0 = blockIdx.x * 64;
  const int r = tid >> 2, c0 = (tid & 3) * 16;
  const float* sp = src + so + (size_t)(k0 + r) * N + n0 + c0;
  #pragma unroll
  for (int cc = 0; cc < 16; cc += 4){
    f32x4 v = *(const f32x4*)(sp + cc);
    t[r][c0+cc] = v[0]; t[r][c0+cc+1] = v[1]; t[r][c0+cc+2] = v[2]; t[r][c0+cc+3] = v[3];
  }
  __syncthreads();
  _Float16* ph = dH + dof + (size_t)(rowOff + n0 + r) * K + k0 + c0;
  _Float16* pl = dL + dof + (size_t)(rowOff + n0 + r) * K + k0 + c0;
  #pragma unroll
  for (int cc = 0; cc < 16; cc += 4){
    f16x4 vh, vl;
    #pragma unroll
    for (int j = 0; j < 4; j++){
      float s = t[c0+cc+j][r] * 1024.0f;
      _Float16 a = (_Float16)s;
      vh[j] = a; vl[j] = (_Float16)(s - (float)a);
    }
    *(f16x4*)(ph + cc) = vh;
    *(f16x4*)(pl + cc) = vl;
  }
}

// ---------------- concat q/k/v biases -> [E][2304] ----------------
__global__ void concat_bias3_k(const float* __restrict__ bq, const float* __restrict__ bk,
    const float* __restrict__ bv, float* __restrict__ dst, int srcStride)
{
  const int e = blockIdx.y;
  const int i = blockIdx.x*256 + threadIdx.x;   // grid.x=3 -> i<768
  dst[(size_t)e*2304 + i]        = bq[(size_t)e*srcStride + i];
  dst[(size_t)e*2304 + 768 + i]  = bk[(size_t)e*srcStride + i];
  dst[(size_t)e*2304 + 1536 + i] = bv[(size_t)e*srcStride + i];
}

// ------- split-f16 3-term MFMA GEMM, single-buffered global_load_lds staging -------
// MT: 128 or 64 row tile.
template<int MT, int BMODE, int OMODE>
__global__ __launch_bounds__(256,2) void gemm_f16s_k(
    const _Float16* __restrict__ AH, const _Float16* __restrict__ AL,
    const _Float16* __restrict__ BH, const _Float16* __restrict__ BL,
    const float* __restrict__ bias, float* __restrict__ C,
    _Float16* __restrict__ Ch, _Float16* __restrict__ Cl,
    int N, int K, long estride, int bias_stride,
    const int* __restrict__ sel, const float* __restrict__ pm)
{
  constexpr int MI = MT / 32;      // m-frags per wave
  constexpr int AI = MT / 64;      // A DMA instrs per wave per H/L tile
  __shared__ _Float16 AsH[MT][32];
  __shared__ _Float16 AsL[MT][32];
  __shared__ _Float16 BsH[128][32];
  __shared__ _Float16 BsL[128][32];
  const int tid = threadIdx.x;
  const int lane = tid & 63, wave = tid >> 6;
  const int wm = wave >> 1, wn = wave & 1;
  int bx, by; swz2d(bx, by);
  const int row0 = by * MT, col0 = bx * 128;
  const _Float16* bh = BH; const _Float16* bl = BL; const float* bp = bias;
  float cs = 1.0f;
  if constexpr (BMODE == 1){
    const int e = sel[row0 >> 9];
    bh += (size_t)e * estride; bl += (size_t)e * estride;
    bp += (size_t)e * bias_stride;
  }
  if constexpr (OMODE == 1) cs = pm[row0 >> 9];

  const int lr = lane >> 2, lk = (lane & 3) * 8;
  const _Float16 *pAH[AI], *pAL[AI], *pBH[2], *pBL[2];
  _Float16 *lAH[AI], *lAL[AI], *lBH[2], *lBL[2];
  #pragma unroll
  for (int j = 0; j < AI; j++){
    const int ia = wave*AI + j;
    pAH[j] = AH + (size_t)(row0 + ia*16 + lr)*K + lk;
    pAL[j] = AL + (size_t)(row0 + ia*16 + lr)*K + lk;
    lAH[j] = &AsH[0][0] + ia*512;
    lAL[j] = &AsL[0][0] + ia*512;
  }
  #pragma unroll
  for (int j = 0; j < 2; j++){
    const int ib = wave*2 + j;
    pBH[j] = bh + (size_t)(col0 + ib*16 + lr)*K + lk;
    pBL[j] = bl + (size_t)(col0 + ib*16 + lr)*K + lk;
    lBH[j] = &BsH[0][0] + ib*512;
    lBL[j] = &BsL[0][0] + ib*512;
  }

  f32x4 acc[MI][4];
  #pragma unroll
  for (int mi=0;mi<MI;mi++)
    #pragma unroll
    for (int ni=0;ni<4;ni++) acc[mi][ni] = (f32x4){0.f,0.f,0.f,0.f};

  for (int k0 = 0; k0 < K; k0 += 32){
    __syncthreads();
    #pragma unroll
    for (int j = 0; j < AI; j++){
      gl_lds16(pAH[j] + k0, lAH[j]);
      gl_lds16(pAL[j] + k0, lAL[j]);
    }
    #pragma unroll
    for (int j = 0; j < 2; j++){
      gl_lds16(pBH[j] + k0, lBH[j]);
      gl_lds16(pBL[j] + k0, lBL[j]);
    }
    __syncthreads();
    f16x8 fah[MI], fal[MI], fbh[4], fbl[4];
    #pragma unroll
    for (int mi=0;mi<MI;mi++){
      const int r = wm*(MT/2) + mi*16 + (lane&15), c = 8*(lane>>4);
      fah[mi] = __builtin_bit_cast(f16x8, *(const u32x4*)&AsH[r][c]);
      fal[mi] = __builtin_bit_cast(f16x8, *(const u32x4*)&AsL[r][c]);
    }
    #pragma unroll
    for (int ni=0;ni<4;ni++){
      const int r = wn*64 + ni*16 + (lane&15), c = 8*(lane>>4);
      fbh[ni] = __builtin_bit_cast(f16x8, *(const u32x4*)&BsH[r][c]);
      fbl[ni] = __builtin_bit_cast(f16x8, *(const u32x4*)&BsL[r][c]);
    }
    #pragma unroll
    for (int mi=0;mi<MI;mi++)
      #pragma unroll
      for (int ni=0;ni<4;ni++){
        acc[mi][ni] = __builtin_amdgcn_mfma_f32_16x16x32_f16(fah[mi], fbh[ni], acc[mi][ni], 0, 0, 0);
        acc[mi][ni] = __builtin_amdgcn_mfma_f32_16x16x32_f16(fah[mi], fbl[ni], acc[mi][ni], 0, 0, 0);
        acc[mi][ni] = __builtin_amdgcn_mfma_f32_16x16x32_f16(fal[mi], fbh[ni], acc[mi][ni], 0, 0, 0);
      }
  }

  const float INV = 1.0f/1048576.0f;   // undo 1024*1024 scaling (exact pow2)
  const int erow = 4*(lane >> 4);
  const int ecol = lane & 15;
  #pragma unroll
  for (int mi=0;mi<MI;mi++)
    #pragma unroll
    for (int ni=0;ni<4;ni++){
      const int c = col0 + wn*64 + ni*16 + ecol;
      const float bb = bp[c];
      #pragma unroll
      for (int r=0;r<4;r++){
        const int R = row0 + wm*(MT/2) + mi*16 + erow + r;
        const float v = acc[mi][ni][r]*INV + bb;
        if constexpr (OMODE == 0){
          C[(size_t)R*N + c] = v;
        } else if constexpr (OMODE == 1){
          C[(size_t)R*N + c] += cs*v;
        } else {
          const float vs = v * 1024.0f;
          const _Float16 hi = (_Float16)vs;
          Ch[(size_t)R*N + c] = hi;
          Cl[(size_t)R*N + c] = (_Float16)(vs - (float)hi);
        }
      }
    }
}

// ------- split-f16 MFMA attention (swapped-QK, in-register softmax) -------
__global__ __launch_bounds__(256,2) void attn_mfma_k(
    const _Float16* __restrict__ qkvH, const _Float16* __restrict__ qkvL,
    const float* __restrict__ mask,
    _Float16* __restrict__ ctxH, _Float16* __restrict__ ctxL)
{
  __shared__ _Float16 Kh[64][72], Kl[64][72];
  __shared__ _Float16 Vh[64][72], Vl[64][72];   // transposed: [d][k]
  __shared__ float msk[64];
  __shared__ float rsi[4][32];
  const int qb = blockIdx.x, h = blockIdx.y, b = blockIdx.z;
  const int tid = threadIdx.x;
  const int l = tid & 63, w = tid >> 6;
  const int l31 = l & 31, g5 = l >> 5;
  const float SC = 1.0f/8388608.0f;   // 2^-20 (split scale) * 1/8 (1/sqrt(64))

  u32x4 qfh[4], qfl[4];
  {
    const size_t qoff = (size_t)(b*Sq + qb*128 + w*32 + l31) * 2304 + h*DHq + g5*8;
    #pragma unroll
    for (int c = 0; c < 4; c++){
      qfh[c] = *(const u32x4*)(qkvH + qoff + c*16);
      qfl[c] = *(const u32x4*)(qkvL + qoff + c*16);
    }
  }
  f32x16 oacc[2];
  #pragma unroll
  for (int nt = 0; nt < 2; nt++)
    #pragma unroll
    for (int i = 0; i < 16; i++) oacc[nt][i] = 0.f;
  float rsl = 0.f;
  const float* mrow = mask + b*Sq;

  for (int kt = 0; kt < 8; kt++){
    __syncthreads();
    {
      const size_t krow = (size_t)(b*Sq + kt*64 + l) * 2304 + 768 + h*DHq;
      #pragma unroll
      for (int i = 0; i < 2; i++){
        const int ch = w + i*4;
        *(u32x4*)&Kh[l][ch*8] = *(const u32x4*)(qkvH + krow + ch*8);
        *(u32x4*)&Kl[l][ch*8] = *(const u32x4*)(qkvL + krow + ch*8);
      }
      const size_t vrow = krow + 768 + w*16;
      f16x8 v0 = __builtin_bit_cast(f16x8, *(const u32x4*)(qkvH + vrow));
      f16x8 v1 = __builtin_bit_cast(f16x8, *(const u32x4*)(qkvH + vrow + 8));
      f16x8 u0 = __builtin_bit_cast(f16x8, *(const u32x4*)(qkvL + vrow));
      f16x8 u1 = __builtin_bit_cast(f16x8, *(const u32x4*)(qkvL + vrow + 8));
      #pragma unroll
      for (int i = 0; i < 8; i++){
        Vh[w*16 + i][l] = v0[i]; Vh[w*16 + 8 + i][l] = v1[i];
        Vl[w*16 + i][l] = u0[i]; Vl[w*16 + 8 + i][l] = u1[i];
      }
      if (tid < 64) msk[tid] = mrow[kt*64 + tid] + 6.9314718055994531f; // + ln(1024)
    }
    __syncthreads();

    f32x16 sacc[2];
    #pragma unroll
    for (int mt = 0; mt < 2; mt++)
      #pragma unroll
      for (int i = 0; i < 16; i++) sacc[mt][i] = 0.f;
    #pragma unroll
    for (int mt = 0; mt < 2; mt++){
      #pragma unroll
      for (int c = 0; c < 4; c++){
        f16x8 kh = __builtin_bit_cast(f16x8, *(const u32x4*)&Kh[mt*32 + l31][c*16 + g5*8]);
        f16x8 kl = __builtin_bit_cast(f16x8, *(const u32x4*)&Kl[mt*32 + l31][c*16 + g5*8]);
        f16x8 qh = __builtin_bit_cast(f16x8, qfh[c]);
        f16x8 ql = __builtin_bit_cast(f16x8, qfl[c]);
        sacc[mt] = __builtin_amdgcn_mfma_f32_32x32x16_f16(kh, qh, sacc[mt], 0, 0, 0);
        sacc[mt] = __builtin_amdgcn_mfma_f32_32x32x16_f16(kh, ql, sacc[mt], 0, 0, 0);
        sacc[mt] = __builtin_amdgcn_mfma_f32_32x32x16_f16(kl, qh, sacc[mt], 0, 0, 0);
      }
    }

    unsigned int hP[2][4][2], lP[2][4][2];
    #pragma unroll
    for (int mt = 0; mt < 2; mt++){
      #pragma unroll
      for (int m = 0; m < 4; m++){
        f32x4 mk = *(const f32x4*)&msk[mt*32 + m*8 + g5*4];
        float p0 = __expf(fmaf(sacc[mt][4*m+0], SC, mk[0]));
        float p1 = __expf(fmaf(sacc[mt][4*m+1], SC, mk[1]));
        float p2 = __expf(fmaf(sacc[mt][4*m+2], SC, mk[2]));
        float p3 = __expf(fmaf(sacc[mt][4*m+3], SC, mk[3]));
        rsl += (p0 + p1) + (p2 + p3);
        f16x2 h0 = cvt_pk(p0, p1);
        f16x2 h1 = cvt_pk(p2, p3);
        f16x2 e0, e1;
        e0[0] = (_Float16)(p0 - (float)h0[0]); e0[1] = (_Float16)(p1 - (float)h0[1]);
        e1[0] = (_Float16)(p2 - (float)h1[0]); e1[1] = (_Float16)(p3 - (float)h1[1]);
        hP[mt][m][0] = __builtin_bit_cast(unsigned int, h0);
        hP[mt][m][1] = __builtin_bit_cast(unsigned int, h1);
        lP[mt][m][0] = __builtin_bit_cast(unsigned int, e0);
        lP[mt][m][1] = __builtin_bit_cast(unsigned int, e1);
      }
    }

    #pragma unroll
    for (int mt = 0; mt < 2; mt++){
      #pragma unroll
      for (int cc = 0; cc < 2; cc++){
        i32x2 sh0 = pl32swap(hP[mt][2*cc][0], hP[mt][2*cc+1][0]);
        i32x2 sh1 = pl32swap(hP[mt][2*cc][1], hP[mt][2*cc+1][1]);
        i32x2 sl0 = pl32swap(lP[mt][2*cc][0], lP[mt][2*cc+1][0]);
        i32x2 sl1 = pl32swap(lP[mt][2*cc][1], lP[mt][2*cc+1][1]);
        u32x4 pah = (u32x4){(unsigned)sh0[0], (unsigned)sh1[0], (unsigned)sh0[1], (unsigned)sh1[1]};
        u32x4 pal = (u32x4){(unsigned)sl0[0], (unsigned)sl1[0], (unsigned)sl0[1], (unsigned)sl1[1]};
        f16x8 ph = __builtin_bit_cast(f16x8, pah);
        f16x8 pe = __builtin_bit_cast(f16x8, pal);
        const int kof = (mt*2 + cc)*16 + g5*8;
        #pragma unroll
        for (int nt = 0; nt < 2; nt++){
          f16x8 vh = __builtin_bit_cast(f16x8, *(const u32x4*)&Vh[nt*32 + l31][kof]);
          f16x8 vl = __builtin_bit_cast(f16x8, *(const u32x4*)&Vl[nt*32 + l31][kof]);
          oacc[nt] = __builtin_amdgcn_mfma_f32_32x32x16_f16(ph, vh, oacc[nt], 0, 0, 0);
          oacc[nt] = __builtin_amdgcn_mfma_f32_32x32x16_f16(ph, vl, oacc[nt], 0, 0, 0);
          oacc[nt] = __builtin_amdgcn_mfma_f32_32x32x16_f16(pe, vh, oacc[nt], 0, 0, 0);
        }
      }
    }
  }

  {
    unsigned int rb = __builtin_bit_cast(unsigned int, rsl);
    i32x2 sw = pl32swap(rb, rb);
    float partner = __builtin_bit_cast(float, (l >= 32) ? sw[0] : sw[1]);
    float tot = rsl + partner;
    if (l < 32) rsi[w][l31] = 1.0f / tot;
  }
  __syncthreads();

  const size_t obase = (size_t)(b*Sq + qb*128 + w*32);
  #pragma unroll
  for (int nt = 0; nt < 2; nt++){
    const int col = h*DHq + nt*32 + l31;
    #pragma unroll
    for (int r = 0; r < 16; r++){
      const int q = (r&3) + 8*(r>>2) + 4*g5;
      const float v = oacc[nt][r] * rsi[w][q];
      const _Float16 hi = (_Float16)v;
      const size_t off = (obase + q)*Dq + col;
      ctxH[off] = hi;
      ctxL[off] = (_Float16)(v - (float)hi);
    }
  }
}

// ---------------- transpose + f32->bf16 (FFN weights -> [N][K] bf16) ----------------
__global__ void transpose_bf16_k(const float* __restrict__ src, unsigned short* __restrict__ dst,
                                 int K, int N)
{
  __shared__ float t[64][65];
  const int tid = threadIdx.x;
  const size_t mo = (size_t)blockIdx.z * K * N;
  const int k0 = blockIdx.y * 64, n0 = blockIdx.x * 64;
  const int r = tid >> 2, c0 = (tid & 3) * 16;
  const float* sp = src + mo + (size_t)(k0 + r) * N + n0 + c0;
  #pragma unroll
  for (int cc = 0; cc < 16; cc += 4){
    f32x4 v = *(const f32x4*)(sp + cc);
    t[r][c0+cc] = v[0]; t[r][c0+cc+1] = v[1]; t[r][c0+cc+2] = v[2]; t[r][c0+cc+3] = v[3];
  }
  __syncthreads();
  unsigned short* dp = dst + mo + (size_t)(n0 + r) * K + k0 + c0;
  u32x4 h0, h1v;
  #pragma unroll
  for (int i = 0; i < 4; i++) h0[i]  = pk2(t[c0+2*i  ][r], t[c0+2*i+1][r]);
  #pragma unroll
  for (int i = 0; i < 4; i++) h1v[i] = pk2(t[c0+8+2*i][r], t[c0+9+2*i][r]);
  *(u32x4*)(dp)     = h0;
  *(u32x4*)(dp + 8) = h1v;
}

// ------- bf16 MFMA GEMM (FFN path), double-buffered staging -------
// MT: 128 or 64 row tile. AMODE: 0 f32 rows reg-staged; 1 f32 rows via tok_idx; 2 bf16 DMA
// OMODE: 0 bf16 store; 1 f32 write+bias; 2 f32 scatter add gate*(res+bias)
template<int MT, int AMODE, int OMODE, bool GELU_, bool GROUPED>
__global__ __launch_bounds__(256,2) void gemm_bf16_k(
    const void* __restrict__ Av, const unsigned short* __restrict__ BT,
    const float* __restrict__ bias, float* __restrict__ Cf, unsigned short* __restrict__ Cb,
    int N, int K,
    const int* __restrict__ tile_g, const int* __restrict__ tile_r0,
    const int* __restrict__ grp_off, const int* __restrict__ n_tiles,
    const int* __restrict__ tok_idx, const float* __restrict__ gate_s,
    size_t bstride, int bias_stride)
{
  constexpr int MI = MT / 32;            // acc rows per wave
  constexpr int AI = MT / 64;            // A DMA instrs per wave (AMODE==2)
  __shared__ unsigned short As[2][MT][32];
  __shared__ unsigned short Bs[2][128][32];
  const int tid = threadIdx.x;
  const int lane = tid & 63, wave = tid >> 6;
  const int wm = wave >> 1, wn = wave & 1;
  int col0, row0, gend = 1 << 30, g = 0;
  if constexpr (GROUPED){
    const int gx = gridDim.x;
    const int nb = gx * gridDim.y;
    const int bid = blockIdx.y * gx + blockIdx.x;
    int lb = bid;
    if ((nb & 7) == 0) lb = (bid & 7) * (nb >> 3) + (bid >> 3);
    const int t = lb / gx;
    col0 = (lb - t * gx) * 128;
    if (t >= *n_tiles) return;
    g = tile_g[t];
    row0 = grp_off[g] + tile_r0[t];
    gend = grp_off[g+1];
  } else {
    int bx, by; swz2d(bx, by);
    row0 = by * MT;
    col0 = bx * 128;
  }
  const unsigned short* Bp = BT + (size_t)g * bstride;
  const float* bp = bias + (size_t)g * bias_stride;

  const int lr = lane >> 2, lk8 = (lane & 3) * 8;
  // B staging: always DMA (2 x 1KB per wave)
  const unsigned short* pB[2];
  #pragma unroll
  for (int j = 0; j < 2; j++){
    const int ib = wave*2 + j;
    pB[j] = Bp + (size_t)(col0 + ib*16 + lr)*K + lk8;
  }
  auto stageB = [&](int c, int kk){
    gl_lds16(pB[0] + kk, &Bs[0][0][0] + c*4096 + (wave*2+0)*512);
    gl_lds16(pB[1] + kk, &Bs[0][0][0] + c*4096 + (wave*2+1)*512);
  };
  // A staging
  const unsigned short* pA2[AI];
  const float* afp = nullptr; int sa_r = 0, sa_k = 0;
  if constexpr (AMODE == 2){
    #pragma unroll
    for (int j = 0; j < AI; j++){
      int r = row0 + (wave*AI + j)*16 + lr;
      if constexpr (GROUPED) r = (r < gend - 1) ? r : (gend - 1);
      pA2[j] = (const unsigned short*)Av + (size_t)r*K + lk8;
    }
  } else {
    sa_r = (MT == 128) ? (tid >> 1) : (tid >> 2);
    sa_k = (MT == 128) ? ((tid & 1) * 16) : ((tid & 3) * 8);
    int arow = row0 + sa_r;
    if constexpr (GROUPED) arow = (arow < gend - 1) ? arow : (gend - 1);
    if constexpr (AMODE == 1) arow = tok_idx[arow];
    afp = (const float*)Av + (size_t)arow * K + sa_k;
  }
  auto stageA2 = [&](int c, int kk){
    #pragma unroll
    for (int j = 0; j < AI; j++)
      gl_lds16(pA2[j] + kk, &As[0][0][0] + c*(MT*32) + (wave*AI + j)*512);
  };

  f32x4 acc[MI][4];
  #pragma unroll
  for (int mi=0;mi<MI;mi++)
    #pragma unroll
    for (int ni=0;ni<4;ni++) acc[mi][ni] = (f32x4){0.f,0.f,0.f,0.f};

  const int nt = K >> 5;
  // ---- prologue: stage tile 0 into buffer 0 ----
  if constexpr (AMODE == 2){
    stageA2(0, 0);
  } else {
    f32x4 f0 = *(const f32x4*)(afp);
    f32x4 f1 = *(const f32x4*)(afp + 4);
    u32x4 al0;
    al0[0]=pk2(f0[0],f0[1]); al0[1]=pk2(f0[2],f0[3]); al0[2]=pk2(f1[0],f1[1]); al0[3]=pk2(f1[2],f1[3]);
    *(u32x4*)&As[0][sa_r][sa_k] = al0;
    if constexpr (MT == 128){
      f32x4 f2 = *(const f32x4*)(afp + 8);
      f32x4 f3 = *(const f32x4*)(afp + 12);
      u32x4 al1;
      al1[0]=pk2(f2[0],f2[1]); al1[1]=pk2(f2[2],f2[3]); al1[2]=pk2(f3[0],f3[1]); al1[3]=pk2(f3[2],f3[3]);
      *(u32x4*)&As[0][sa_r][sa_k + 8] = al1;
    }
  }
  stageB(0, 0);

  int cur = 0;
  for (int t = 0; t < nt; t++){
    __syncthreads();                      // tile t ready (DMA drained, ds_writes visible)
    const int k1 = (t + 1) << 5;
    f32x4 f0n, f1n, f2n, f3n;
    const bool nxt = (t + 1 < nt);
    if (nxt){
      if constexpr (AMODE == 2){
        stageA2(cur ^ 1, k1);
      } else {
        f0n = *(const f32x4*)(afp + k1);
        f1n = *(const f32x4*)(afp + k1 + 4);
        if constexpr (MT == 128){
          f2n = *(const f32x4*)(afp + k1 + 8);
          f3n = *(const f32x4*)(afp + k1 + 12);
        }
      }
      stageB(cur ^ 1, k1);
    }
    bf16x8 af[MI], bfr[4];
    #pragma unroll
    for (int mi=0;mi<MI;mi++){
      u32x4 tt = *(const u32x4*)&As[cur][wm*(MT/2) + mi*16 + (lane&15)][8*(lane>>4)];
      af[mi] = __builtin_bit_cast(bf16x8, tt);
    }
    #pragma unroll
    for (int ni=0;ni<4;ni++){
      u32x4 tt = *(const u32x4*)&Bs[cur][wn*64 + ni*16 + (lane&15)][8*(lane>>4)];
      bfr[ni] = __builtin_bit_cast(bf16x8, tt);
    }
    #pragma unroll
    for (int mi=0;mi<MI;mi++)
      #pragma unroll
      for (int ni=0;ni<4;ni++)
        acc[mi][ni] = __builtin_amdgcn_mfma_f32_16x16x32_bf16(af[mi], bfr[ni], acc[mi][ni], 0, 0, 0);
    if (nxt){
      if constexpr (AMODE != 2){
        u32x4 al0;
        al0[0]=pk2(f0n[0],f0n[1]); al0[1]=pk2(f0n[2],f0n[3]); al0[2]=pk2(f1n[0],f1n[1]); al0[3]=pk2(f1n[2],f1n[3]);
        *(u32x4*)&As[cur^1][sa_r][sa_k] = al0;
        if constexpr (MT == 128){
          u32x4 al1;
          al1[0]=pk2(f2n[0],f2n[1]); al1[1]=pk2(f2n[2],f2n[3]); al1[2]=pk2(f3n[0],f3n[1]); al1[3]=pk2(f3n[2],f3n[3]);
          *(u32x4*)&As[cur^1][sa_r][sa_k + 8] = al1;
        }
      }
    }
    cur ^= 1;
  }

  const int erow = 4*(lane >> 4);
  const int ecol = lane & 15;
  #pragma unroll
  for (int mi=0;mi<MI;mi++)
    #pragma unroll
    for (int ni=0;ni<4;ni++){
      const int c = col0 + wn*64 + ni*16 + ecol;
      const float bb = bp[c];
      #pragma unroll
      for (int r=0;r<4;r++){
        const int R = row0 + wm*(MT/2) + mi*16 + erow + r;
        if (GROUPED && R >= gend) continue;
        float v = acc[mi][ni][r] + bb;
        if (GELU_) v = 0.5f*v*(1.0f + erff(v*0.70710678118654752f));
        if constexpr (OMODE == 0){
          Cb[(size_t)R*N + c] = f2bf(v);
        } else if constexpr (OMODE == 1){
          Cf[(size_t)R*N + c] = v;
        } else {
          const int tok = tok_idx[R];
          const float gt = gate_s[R];
          float* p = Cf + (size_t)tok*N + c;
          *p += gt*v;
        }
      }
    }
}

// ---------------- token-level switch router (f32, one wave/token) ----------------
__global__ void token_router_k(const float* __restrict__ att, const int* __restrict__ sel,
    const float* __restrict__ sww, const float* __restrict__ swb,
    int* __restrict__ grp, float* __restrict__ gate, int* __restrict__ grp_cnt)
{
  const int t = blockIdx.x*4 + (threadIdx.x >> 6);
  const int lane = threadIdx.x & 63;
  const int e = sel[t >> 9];
  const float* x = att + (size_t)t * Dq;
  const float* w = sww + (size_t)e * Dq * 4;
  float a0=0.f, a1=0.f, a2=0.f, a3=0.f;
  #pragma unroll 4
  for (int i = 0; i < 12; i++){
    const int d = lane + i*64;
    const float xv = x[d];
    f32x4 wv = *(const f32x4*)&w[d*4];
    a0 += xv*wv[0]; a1 += xv*wv[1]; a2 += xv*wv[2]; a3 += xv*wv[3];
  }
  #pragma unroll
  for (int off = 32; off; off >>= 1){
    a0 += __shfl_xor(a0, off); a1 += __shfl_xor(a1, off);
    a2 += __shfl_xor(a2, off); a3 += __shfl_xor(a3, off);
  }
  if (lane == 0){
    const float l0 = a0 + swb[e*4+0], l1 = a1 + swb[e*4+1];
    const float l2 = a2 + swb[e*4+2], l3 = a3 + swb[e*4+3];
    const float mx = fmaxf(fmaxf(l0,l1), fmaxf(l2,l3));
    const float p0 = expf(l0-mx), p1 = expf(l1-mx), p2 = expf(l2-mx), p3 = expf(l3-mx);
    const float ssum = p0+p1+p2+p3;
    int am = 0; float bv = p0;
    if (p1 > bv){ bv=p1; am=1; }
    if (p2 > bv){ bv=p2; am=2; }
    if (p3 > bv){ bv=p3; am=3; }
    grp[t] = e*4 + am;
    gate[t] = bv/ssum;
    atomicAdd(&grp_cnt[e*4 + am], 1);
  }
}

__global__ void build_offsets_k(const int* __restrict__ grp_cnt, int* __restrict__ grp_off,
    int* __restrict__ tg128, int* __restrict__ tr128, int* __restrict__ nt128,
    int* __restrict__ tg64, int* __restrict__ tr64, int* __restrict__ nt64)
{
  int off = 0, n1 = 0, n2 = 0;
  for (int g = 0; g < 16; g++){
    grp_off[g] = off;
    const int c = grp_cnt[g];
    for (int r0 = 0; r0 < c; r0 += 128){ tg128[n1] = g; tr128[n1] = r0; n1++; }
    for (int r0 = 0; r0 < c; r0 += 64){  tg64[n2]  = g; tr64[n2]  = r0; n2++; }
    off += c;
  }
  grp_off[16] = off;
  *nt128 = n1; *nt64 = n2;
}

__global__ void scatter_k(const int* __restrict__ grp, const float* __restrict__ gate,
    const int* __restrict__ grp_off, int* __restrict__ fill,
    int* __restrict__ tok_idx, float* __restrict__ gate_s)
{
  const int t = blockIdx.x*256 + threadIdx.x;
  const int g = grp[t];
  const int pos = grp_off[g] + atomicAdd(&fill[g], 1);
  tok_idx[pos] = t;
  gate_s[pos] = gate[t];
}

// ---------------- final residual-add + LayerNorm ----------------
__global__ __launch_bounds__(256) void final_ln_k(const float* __restrict__ att,
    const float* __restrict__ acc, const float* __restrict__ lg,
    const float* __restrict__ lb, float* __restrict__ out)
{
  const int row = blockIdx.x, tid = threadIdx.x;
  const float* a = att + (size_t)row * Dq;
  const float* c = acc + (size_t)row * Dq;
  float x[3];
  #pragma unroll
  for (int i = 0; i < 3; i++) x[i] = a[tid + 256*i] + c[tid + 256*i];
  __shared__ float red[256];
  red[tid] = x[0] + x[1] + x[2];
  __syncthreads();
  for (int st = 128; st; st >>= 1){
    if (tid < st) red[tid] += red[tid + st];
    __syncthreads();
  }
  const float mu = red[0] * (1.0f/768.0f);
  __syncthreads();
  const float d0 = x[0]-mu, d1 = x[1]-mu, d2 = x[2]-mu;
  red[tid] = d0*d0 + d1*d1 + d2*d2;
  __syncthreads();
  for (int st = 128; st; st >>= 1){
    if (tid < st) red[tid] += red[tid + st];
    __syncthreads();
  }
  const float inv = 1.0f/sqrtf(red[0]*(1.0f/768.0f) + 1e-12f);
  #pragma unroll
  for (int i = 0; i < 3; i++){
    const int col = tid + 256*i;
    out[(size_t)row*Dq + col] = (x[i]-mu)*inv*lg[col] + lb[col];
  }
}

// ======================= launch =======================
extern "C" void kernel_launch(void* const* d_in, const int* in_sizes, int n_in,
                              void* d_out, int out_size, void* d_ws, size_t ws_size,
                              hipStream_t stream)
{
  (void)in_sizes; (void)n_in; (void)out_size; (void)ws_size;
  const float* hs    = (const float*)d_in[0];
  const float* amask = (const float*)d_in[1];
  const float* sw_enc_w = (const float*)d_in[3];
  const float* sw_enc_b = (const float*)d_in[4];
  const float* sw_w  = (const float*)d_in[5];
  const float* sw_b  = (const float*)d_in[6];
  const float* ca_wq = (const float*)d_in[7];
  const float* ca_bq = (const float*)d_in[8];
  const float* ca_wk = (const float*)d_in[9];
  const float* ca_bk = (const float*)d_in[10];
  const float* ca_wv = (const float*)d_in[11];
  const float* ca_bv = (const float*)d_in[12];
  const float* ca_wo = (const float*)d_in[13];
  const float* ca_bo = (const float*)d_in[14];
  const float* ua_wq = (const float*)d_in[15];
  const float* ua_bq = (const float*)d_in[16];
  const float* ua_wk = (const float*)d_in[17];
  const float* ua_bk = (const float*)d_in[18];
  const float* ua_wv = (const float*)d_in[19];
  const float* ua_bv = (const float*)d_in[20];
  const float* ua_wo = (const float*)d_in[21];
  const float* ua_bo = (const float*)d_in[22];
  const float* cf_w1 = (const float*)d_in[23];
  const float* cf_b1 = (const float*)d_in[24];
  const float* cf_w2 = (const float*)d_in[25];
  const float* cf_b2 = (const float*)d_in[26];
  const float* uf_sw_w = (const float*)d_in[27];
  const float* uf_sw_b = (const float*)d_in[28];
  const float* uf_w1 = (const float*)d_in[29];
  const float* uf_b1 = (const float*)d_in[30];
  const float* uf_w2 = (const float*)d_in[31];
  const float* uf_b2 = (const float*)d_in[32];
  const float* ln_g  = (const float*)d_in[33];
  const float* ln_b  = (const float*)d_in[34];
  float* out = (float*)d_out;

  char* W = (char*)d_ws;
  // control block
  int*   sel     = (int*)(W + 0);
  float* pm      = (float*)(W + 64);
  int*   grp_cnt = (int*)(W + 128);
  int*   fill    = (int*)(W + 192);
  int*   ntile   = (int*)(W + 256);
  int*   ntile64 = (int*)(W + 320);
  int*   grp_off = (int*)(W + 512);
  int*   tile_g  = (int*)(W + 1024);
  int*   tile_r  = (int*)(W + 2048);
  int*   tile_g64= (int*)(W + 3072);
  int*   tile_r64= (int*)(W + 4096);

  float* att  = (float*)(W + 8192);             // [8192][768] f32
  float* facc = (float*)(W + 25174016);         // [8192][768] f32
  const size_t X = 50339840;
  _Float16* hsH  = (_Float16*)(W + X);                 // 12,582,912
  _Float16* hsL  = (_Float16*)(W + X + 12582912);
  _Float16* qkvH = (_Float16*)(W + X + 25165824);      // 37,748,736
  _Float16* qkvL = (_Float16*)(W + X + 62914560);      // end X+100663296
  _Float16* ctxH = (_Float16*)(W + X + 100663296);     // 12,582,912
  _Float16* ctxL = (_Float16*)(W + X + 113246208);     // end X+125829120
  _Float16* wqkv_cH = (_Float16*)(W + X + 125829120);  // 3,538,944
  _Float16* wqkv_cL = (_Float16*)(W + X + 129368064);
  _Float16* wqkv_uH = (_Float16*)(W + X + 132907008);  // 14,155,776
  _Float16* wqkv_uL = (_Float16*)(W + X + 147062784);
  _Float16* wo_cH   = (_Float16*)(W + X + 161218560);  // 1,179,648
  _Float16* wo_cL   = (_Float16*)(W + X + 162398208);
  _Float16* wo_uH   = (_Float16*)(W + X + 163577856);  // 4,718,592
  _Float16* wo_uL   = (_Float16*)(W + X + 168296448);  // end X+173015040
  float* qkvb_c = (float*)(W + X + 173015040);         // 9,216
  float* qkvb_u = (float*)(W + X + 173024256);         // 36,864
  float* partb  = (float*)(W + X + 173061120);         // 196,608

  // phase B (after attention) reuses phase-A scratch:
  unsigned short* w1T = (unsigned short*)(W + X);              // 80,216,064
  unsigned short* w2T = (unsigned short*)(W + X + 80216064);   // end X+160432128
  unsigned short* h1  = (unsigned short*)(W + X + 160432128);  // 50,331,648
  int*   grp     = (int*)(W + 261103616);
  float* gate    = (float*)(W + 261136384);
  int*   tok_idx = (int*)(W + 261169152);
  float* gate_s  = (float*)(W + 261201920);

  hipMemsetAsync(W, 0, 512, stream);

  // ---- sequence router (exact f32) ----
  pooled_partial_k<<<dim3(Bq,3,4),256,0,stream>>>(hs, partb);
  router_seq_k<<<Bq,128,0,stream>>>(partb, sw_enc_w, sw_enc_b, sw_w, sw_b, sel, pm);

  // ---- prepare split-f16 operands ----
  split_f16_k<<<6144,256,0,stream>>>(hs, hsH, hsL, NTq*Dq/4);
  transpose_f16s_k<<<dim3(12,12,1),256,0,stream>>>(ca_wq, wqkv_cH, wqkv_cL, Dq, Dq, 0, 0, 0);
  transpose_f16s_k<<<dim3(12,12,1),256,0,stream>>>(ca_wk, wqkv_cH, wqkv_cL, Dq, Dq, 0, 0, 768);
  transpose_f16s_k<<<dim3(12,12,1),256,0,stream>>>(ca_wv, wqkv_cH, wqkv_cL, Dq, Dq, 0, 0, 1536);
  transpose_f16s_k<<<dim3(12,12,4),256,0,stream>>>(ua_wq, wqkv_uH, wqkv_uL, Dq, Dq, (long)Dq*Dq, (long)2304*768, 0);
  transpose_f16s_k<<<dim3(12,12,4),256,0,stream>>>(ua_wk, wqkv_uH, wqkv_uL, Dq, Dq, (long)Dq*Dq, (long)2304*768, 768);
  transpose_f16s_k<<<dim3(12,12,4),256,0,stream>>>(ua_wv, wqkv_uH, wqkv_uL, Dq, Dq, (long)Dq*Dq, (long)2304*768, 1536);
  transpose_f16s_k<<<dim3(12,12,1),256,0,stream>>>(ca_wo, wo_cH, wo_cL, Dq, Dq, 0, 0, 0);
  transpose_f16s_k<<<dim3(12,12,4),256,0,stream>>>(ua_wo, wo_uH, wo_uL, Dq, Dq, (long)Dq*Dq, (long)Dq*Dq, 0);
  concat_bias3_k<<<dim3(3,1),256,0,stream>>>(ca_bq, ca_bk, ca_bv, qkvb_c, 0);
  concat_bias3_k<<<dim3(3,4),256,0,stream>>>(ua_bq, ua_bk, ua_bv, qkvb_u, 768);

  // ---- common attention ----
  gemm_f16s_k<128,0,2><<<dim3(18,64),256,0,stream>>>(hsH, hsL, wqkv_cH, wqkv_cL, qkvb_c,
      nullptr, qkvH, qkvL, 2304, Dq, 0, 0, nullptr, nullptr);
  attn_mfma_k<<<dim3(4,Hq,Bq),256,0,stream>>>(qkvH, qkvL, amask, ctxH, ctxL);
  gemm_f16s_k<64,0,0><<<dim3(6,128),256,0,stream>>>(ctxH, ctxL, wo_cH, wo_cL, ca_bo,
      att, nullptr, nullptr, Dq, Dq, 0, 0, nullptr, nullptr);

  // ---- unique attention (selected expert), att += pm * result ----
  gemm_f16s_k<128,1,2><<<dim3(18,64),256,0,stream>>>(hsH, hsL, wqkv_uH, wqkv_uL, qkvb_u,
      nullptr, qkvH, qkvL, 2304, Dq, (long)2304*768, 2304, sel, nullptr);
  attn_mfma_k<<<dim3(4,Hq,Bq),256,0,stream>>>(qkvH, qkvL, amask, ctxH, ctxL);
  gemm_f16s_k<64,1,1><<<dim3(6,128),256,0,stream>>>(ctxH, ctxL, wo_uH, wo_uL, ua_bo,
      att, nullptr, nullptr, Dq, Dq, (long)Dq*Dq, Dq, sel, pm);

  // ---- FFN weights -> transposed bf16 (phase-A scratch now free) ----
  transpose_bf16_k<<<dim3(48,12,1), 256,0,stream>>>(cf_w1, w1T, Dq, Fq);
  transpose_bf16_k<<<dim3(48,12,16),256,0,stream>>>(uf_w1, w1T + 2359296, Dq, Fq);
  transpose_bf16_k<<<dim3(12,48,1), 256,0,stream>>>(cf_w2, w2T, Fq, Dq);
  transpose_bf16_k<<<dim3(12,48,16),256,0,stream>>>(uf_w2, w2T + 2359296, Fq, Dq);

  // ---- common FFN (bf16 MFMA) ----
  gemm_bf16_k<128,0,0,true,false><<<dim3(24,64),256,0,stream>>>((const void*)att, w1T, cf_b1, nullptr, h1,
      Fq, Dq, nullptr,nullptr,nullptr,nullptr,nullptr,nullptr, (size_t)0, 0);
  gemm_bf16_k<64,2,1,false,false><<<dim3(6,128),256,0,stream>>>((const void*)h1, w2T, cf_b2, facc, nullptr,
      Dq, Fq, nullptr,nullptr,nullptr,nullptr,nullptr,nullptr, (size_t)0, 0);

  // ---- token routing (f32, on accurate att) ----
  token_router_k<<<2048,256,0,stream>>>(att, sel, uf_sw_w, uf_sw_b, grp, gate, grp_cnt);
  build_offsets_k<<<1,1,0,stream>>>(grp_cnt, grp_off, tile_g, tile_r, ntile, tile_g64, tile_r64, ntile64);
  scatter_k<<<32,256,0,stream>>>(grp, gate, grp_off, fill, tok_idx, gate_s);

  // ---- unique FFN (grouped, top-1 inner expert, gated scatter-add) ----
  gemm_bf16_k<128,1,0,true,true><<<dim3(24,80),256,0,stream>>>((const void*)att, w1T + 2359296, uf_b1, nullptr, h1,
      Fq, Dq, tile_g, tile_r, grp_off, ntile, tok_idx, gate_s, (size_t)2359296, Fq);
  gemm_bf16_k<64,2,2,false,true><<<dim3(6,144),256,0,stream>>>((const void*)h1, w2T + 2359296, uf_b2, facc, nullptr,
      Dq, Fq, tile_g64, tile_r64, grp_off, ntile64, tok_idx, gate_s, (size_t)2359296, Dq);

  // ---- residual + LayerNorm ----
  final_ln_k<<<NTq,256,0,stream>>>(att, facc, ln_g, ln_b, out);
}

// Round 10
// 1132.626 us; speedup vs baseline: 1.0366x; 1.0137x over previous
//
#include <hip/hip_runtime.h>
#include <cstdint>
#include <cstddef>

#define Bq  16
#define Sq  512
#define Dq  768
#define Hq  12
#define DHq 64
#define Fq  3072
#define SWq 128
#define NTq 8192

typedef float        f32x4  __attribute__((ext_vector_type(4)));
typedef float        f32x16 __attribute__((ext_vector_type(16)));
typedef unsigned int u32x4  __attribute__((ext_vector_type(4)));
typedef __bf16       bf16x8 __attribute__((ext_vector_type(8)));
typedef _Float16     f16x8  __attribute__((ext_vector_type(8)));
typedef _Float16     f16x4  __attribute__((ext_vector_type(4)));
typedef _Float16     f16x2  __attribute__((ext_vector_type(2)));
typedef int          i32x2  __attribute__((ext_vector_type(2)));

__device__ __forceinline__ unsigned short f2bf(float f){
  unsigned int u = __builtin_bit_cast(unsigned int, f);
  u = (u + 0x7fffu + ((u >> 16) & 1u)) >> 16;
  return (unsigned short)u;
}
__device__ __forceinline__ unsigned int pk2(float a, float b){
  return (unsigned int)f2bf(a) | ((unsigned int)f2bf(b) << 16);
}
__device__ __forceinline__ i32x2 pl32swap(unsigned int a, unsigned int b){
  return __builtin_amdgcn_permlane32_swap((int)a, (int)b, false, false);
}
__device__ __forceinline__ f16x2 cvt_pk(float a, float b){
  return __builtin_bit_cast(f16x2, __builtin_amdgcn_cvt_pkrtz(a, b));
}

// async global->LDS DMA, 16B per lane. LDS dest = wave-uniform base + lane*16.
typedef __attribute__((address_space(1))) void vg_t;
typedef __attribute__((address_space(3))) void vl_t;
__device__ __forceinline__ void gl_lds16(const void* g, void* l){
  __builtin_amdgcn_global_load_lds((vg_t*)g, (vl_t*)l, 16, 0, 0);
}

// Band-supertile + XCD-aware bijective block remap (non-grouped GEMMs).
__device__ __forceinline__ void swz2d(int &bx, int &by){
  const int gx = gridDim.x, gy = gridDim.y;
  const int nb = gx * gy;
  const int bid = blockIdx.y * gx + blockIdx.x;
  if (((nb & 7) == 0) && ((gy & 7) == 0)){
    const int chunk = nb >> 3;
    const int lb = (bid & 7) * chunk + (bid >> 3);
    const int bw = gx << 3;              // blocks per band
    const int band = lb / bw;
    const int wn = lb - band * bw;
    bx = wn >> 3;
    by = (band << 3) + (wn & 7);
  } else {
    bx = blockIdx.x; by = blockIdx.y;
  }
}

// ---------------- pooled partial sums (seq router input) ----------------
__global__ void pooled_partial_k(const float* __restrict__ x, float* __restrict__ part){
  const int b = blockIdx.x, dc = blockIdx.y, z = blockIdx.z;
  const int d = dc*256 + threadIdx.x;
  const float* p = x + (size_t)b*Sq*Dq + (size_t)z*128*Dq + d;
  float s = 0.f;
  #pragma unroll 4
  for (int i = 0; i < 128; i++) s += p[(size_t)i*Dq];
  part[((size_t)z*Bq + b)*Dq + d] = s;
}

// ---------------- sequence-level router (exact f32) ----------------
__global__ void router_seq_k(const float* __restrict__ part,
    const float* __restrict__ ew, const float* __restrict__ eb,
    const float* __restrict__ sw, const float* __restrict__ sb,
    int* __restrict__ sel, float* __restrict__ pm)
{
  const int b = blockIdx.x, j = threadIdx.x;   // 128 threads
  __shared__ float h[SWq];
  __shared__ float pl[Dq];
  #pragma unroll
  for (int i = 0; i < 6; i++){
    int d = j + i*128;
    float s = part[(size_t)(0*Bq+b)*Dq + d] + part[(size_t)(1*Bq+b)*Dq + d]
            + part[(size_t)(2*Bq+b)*Dq + d] + part[(size_t)(3*Bq+b)*Dq + d];
    pl[d] = s * (1.0f/512.0f);
  }
  __syncthreads();
  float a = eb[j];
  for (int d = 0; d < Dq; d++) a += pl[d] * ew[d*SWq + j];
  h[j] = a;
  __syncthreads();
  if (j == 0){
    float lg[4];
    for (int e = 0; e < 4; e++){
      float t = sb[e];
      for (int k = 0; k < SWq; k++) t += h[k] * sw[k*4 + e];
      lg[e] = t;
    }
    float mx = fmaxf(fmaxf(lg[0],lg[1]), fmaxf(lg[2],lg[3]));
    float p[4], ssum = 0.f;
    for (int e = 0; e < 4; e++){ p[e] = expf(lg[e]-mx); ssum += p[e]; }
    int am = 0; float bv = p[0];
    for (int e = 1; e < 4; e++) if (p[e] > bv){ bv = p[e]; am = e; }
    sel[b] = am; pm[b] = bv/ssum;
  }
}

// ---------------- f32 -> f16 hi/lo split (x1024 scale) ----------------
__global__ void split_f16_k(const float* __restrict__ x, _Float16* __restrict__ hh,
                            _Float16* __restrict__ ll, int n4){
  const int i = blockIdx.x*256 + threadIdx.x;
  if (i >= n4) return;
  f32x4 v = ((const f32x4*)x)[i];
  f16x4 vh, vl;
  #pragma unroll
  for (int j = 0; j < 4; j++){
    float s = v[j] * 1024.0f;
    _Float16 a = (_Float16)s;
    vh[j] = a;
    vl[j] = (_Float16)(s - (float)a);
  }
  ((f16x4*)hh)[i] = vh;
  ((f16x4*)ll)[i] = vl;
}

// ------- weight transpose + f16 hi/lo split: src [K][N] -> dst [N][K] x1024 -------
__global__ void transpose_f16s_k(const float* __restrict__ src,
    _Float16* __restrict__ dH, _Float16* __restrict__ dL,
    int K, int N, long srcStride, long dstStride, int rowOff)
{
  __shared__ float t[64][65];
  const int tid = threadIdx.x;
  const size_t so = (size_t)blockIdx.z * srcStride;
  const size_t dof = (size_t)blockIdx.z * dstStride;
  const int k0 = blockIdx.y * 64, n0 = blockIdx.x * 64;
  const int r = tid >> 2, c0 = (tid & 3) * 16;
  const float* sp = src + so + (size_t)(k0 + r) * N + n0 + c0;
  #pragma unroll
  for (int cc = 0; cc < 16; cc += 4){
    f32x4 v = *(const f32x4*)(sp + cc);
    t[r][c0+cc] = v[0]; t[r][c0+cc+1] = v[1]; t[r][c0+cc+2] = v[2]; t[r][c0+cc+3] = v[3];
  }
  __syncthreads();
  _Float16* ph = dH + dof + (size_t)(rowOff + n0 + r) * K + k0 + c0;
  _Float16* pl = dL + dof + (size_t)(rowOff + n0 + r) * K + k0 + c0;
  #pragma unroll
  for (int cc = 0; cc < 16; cc += 4){
    f16x4 vh, vl;
    #pragma unroll
    for (int j = 0; j < 4; j++){
      float s = t[c0+cc+j][r] * 1024.0f;
      _Float16 a = (_Float16)s;
      vh[j] = a; vl[j] = (_Float16)(s - (float)a);
    }
    *(f16x4*)(ph + cc) = vh;
    *(f16x4*)(pl + cc) = vl;
  }
}

// ---------------- concat q/k/v biases -> [E][2304] ----------------
__global__ void concat_bias3_k(const float* __restrict__ bq, const float* __restrict__ bk,
    const float* __restrict__ bv, float* __restrict__ dst, int srcStride)
{
  const int e = blockIdx.y;
  const int i = blockIdx.x*256 + threadIdx.x;   // grid.x=3 -> i<768
  dst[(size_t)e*2304 + i]        = bq[(size_t)e*srcStride + i];
  dst[(size_t)e*2304 + 768 + i]  = bk[(size_t)e*srcStride + i];
  dst[(size_t)e*2304 + 1536 + i] = bv[(size_t)e*srcStride + i];
}

// ------- split-f16 3-term MFMA GEMM, single-buffered global_load_lds staging -------
// MT: 128 or 64 row tile.
// OMODE: 0 C=v (+bf16 mirror Cb16); 1 C += pm*v (+bf16 mirror of new value); 2 split-f16 store
template<int MT, int BMODE, int OMODE>
__global__ __launch_bounds__(256,2) void gemm_f16s_k(
    const _Float16* __restrict__ AH, const _Float16* __restrict__ AL,
    const _Float16* __restrict__ BH, const _Float16* __restrict__ BL,
    const float* __restrict__ bias, float* __restrict__ C,
    _Float16* __restrict__ Ch, _Float16* __restrict__ Cl,
    unsigned short* __restrict__ Cb16,
    int N, int K, long estride, int bias_stride,
    const int* __restrict__ sel, const float* __restrict__ pm)
{
  constexpr int MI = MT / 32;      // m-frags per wave
  constexpr int AI = MT / 64;      // A DMA instrs per wave per H/L tile
  __shared__ _Float16 AsH[MT][32];
  __shared__ _Float16 AsL[MT][32];
  __shared__ _Float16 BsH[128][32];
  __shared__ _Float16 BsL[128][32];
  const int tid = threadIdx.x;
  const int lane = tid & 63, wave = tid >> 6;
  const int wm = wave >> 1, wn = wave & 1;
  int bx, by; swz2d(bx, by);
  const int row0 = by * MT, col0 = bx * 128;
  const _Float16* bh = BH; const _Float16* bl = BL; const float* bp = bias;
  float cs = 1.0f;
  if constexpr (BMODE == 1){
    const int e = sel[row0 >> 9];
    bh += (size_t)e * estride; bl += (size_t)e * estride;
    bp += (size_t)e * bias_stride;
  }
  if constexpr (OMODE == 1) cs = pm[row0 >> 9];

  const int lr = lane >> 2, lk = (lane & 3) * 8;
  const _Float16 *pAH[AI], *pAL[AI], *pBH[2], *pBL[2];
  _Float16 *lAH[AI], *lAL[AI], *lBH[2], *lBL[2];
  #pragma unroll
  for (int j = 0; j < AI; j++){
    const int ia = wave*AI + j;
    pAH[j] = AH + (size_t)(row0 + ia*16 + lr)*K + lk;
    pAL[j] = AL + (size_t)(row0 + ia*16 + lr)*K + lk;
    lAH[j] = &AsH[0][0] + ia*512;
    lAL[j] = &AsL[0][0] + ia*512;
  }
  #pragma unroll
  for (int j = 0; j < 2; j++){
    const int ib = wave*2 + j;
    pBH[j] = bh + (size_t)(col0 + ib*16 + lr)*K + lk;
    pBL[j] = bl + (size_t)(col0 + ib*16 + lr)*K + lk;
    lBH[j] = &BsH[0][0] + ib*512;
    lBL[j] = &BsL[0][0] + ib*512;
  }

  f32x4 acc[MI][4];
  #pragma unroll
  for (int mi=0;mi<MI;mi++)
    #pragma unroll
    for (int ni=0;ni<4;ni++) acc[mi][ni] = (f32x4){0.f,0.f,0.f,0.f};

  for (int k0 = 0; k0 < K; k0 += 32){
    __syncthreads();
    #pragma unroll
    for (int j = 0; j < AI; j++){
      gl_lds16(pAH[j] + k0, lAH[j]);
      gl_lds16(pAL[j] + k0, lAL[j]);
    }
    #pragma unroll
    for (int j = 0; j < 2; j++){
      gl_lds16(pBH[j] + k0, lBH[j]);
      gl_lds16(pBL[j] + k0, lBL[j]);
    }
    __syncthreads();
    f16x8 fah[MI], fal[MI], fbh[4], fbl[4];
    #pragma unroll
    for (int mi=0;mi<MI;mi++){
      const int r = wm*(MT/2) + mi*16 + (lane&15), c = 8*(lane>>4);
      fah[mi] = __builtin_bit_cast(f16x8, *(const u32x4*)&AsH[r][c]);
      fal[mi] = __builtin_bit_cast(f16x8, *(const u32x4*)&AsL[r][c]);
    }
    #pragma unroll
    for (int ni=0;ni<4;ni++){
      const int r = wn*64 + ni*16 + (lane&15), c = 8*(lane>>4);
      fbh[ni] = __builtin_bit_cast(f16x8, *(const u32x4*)&BsH[r][c]);
      fbl[ni] = __builtin_bit_cast(f16x8, *(const u32x4*)&BsL[r][c]);
    }
    #pragma unroll
    for (int mi=0;mi<MI;mi++)
      #pragma unroll
      for (int ni=0;ni<4;ni++){
        acc[mi][ni] = __builtin_amdgcn_mfma_f32_16x16x32_f16(fah[mi], fbh[ni], acc[mi][ni], 0, 0, 0);
        acc[mi][ni] = __builtin_amdgcn_mfma_f32_16x16x32_f16(fah[mi], fbl[ni], acc[mi][ni], 0, 0, 0);
        acc[mi][ni] = __builtin_amdgcn_mfma_f32_16x16x32_f16(fal[mi], fbh[ni], acc[mi][ni], 0, 0, 0);
      }
  }

  const float INV = 1.0f/1048576.0f;   // undo 1024*1024 scaling (exact pow2)
  const int erow = 4*(lane >> 4);
  const int ecol = lane & 15;
  #pragma unroll
  for (int mi=0;mi<MI;mi++)
    #pragma unroll
    for (int ni=0;ni<4;ni++){
      const int c = col0 + wn*64 + ni*16 + ecol;
      const float bb = bp[c];
      #pragma unroll
      for (int r=0;r<4;r++){
        const int R = row0 + wm*(MT/2) + mi*16 + erow + r;
        const float v = acc[mi][ni][r]*INV + bb;
        if constexpr (OMODE == 0){
          C[(size_t)R*N + c] = v;
          Cb16[(size_t)R*N + c] = f2bf(v);
        } else if constexpr (OMODE == 1){
          const float val = C[(size_t)R*N + c] + cs*v;
          C[(size_t)R*N + c] = val;
          Cb16[(size_t)R*N + c] = f2bf(val);
        } else {
          const float vs = v * 1024.0f;
          const _Float16 hi = (_Float16)vs;
          Ch[(size_t)R*N + c] = hi;
          Cl[(size_t)R*N + c] = (_Float16)(vs - (float)hi);
        }
      }
    }
}

// ------- split-f16 MFMA attention (swapped-QK, in-register softmax) -------
__global__ __launch_bounds__(256,2) void attn_mfma_k(
    const _Float16* __restrict__ qkvH, const _Float16* __restrict__ qkvL,
    const float* __restrict__ mask,
    _Float16* __restrict__ ctxH, _Float16* __restrict__ ctxL)
{
  __shared__ _Float16 Kh[64][72], Kl[64][72];
  __shared__ _Float16 Vh[64][72], Vl[64][72];   // transposed: [d][k]
  __shared__ float msk[64];
  __shared__ float rsi[4][32];
  const int qb = blockIdx.x, h = blockIdx.y, b = blockIdx.z;
  const int tid = threadIdx.x;
  const int l = tid & 63, w = tid >> 6;
  const int l31 = l & 31, g5 = l >> 5;
  const float SC = 1.0f/8388608.0f;   // 2^-20 (split scale) * 1/8 (1/sqrt(64))

  u32x4 qfh[4], qfl[4];
  {
    const size_t qoff = (size_t)(b*Sq + qb*128 + w*32 + l31) * 2304 + h*DHq + g5*8;
    #pragma unroll
    for (int c = 0; c < 4; c++){
      qfh[c] = *(const u32x4*)(qkvH + qoff + c*16);
      qfl[c] = *(const u32x4*)(qkvL + qoff + c*16);
    }
  }
  f32x16 oacc[2];
  #pragma unroll
  for (int nt = 0; nt < 2; nt++)
    #pragma unroll
    for (int i = 0; i < 16; i++) oacc[nt][i] = 0.f;
  float rsl = 0.f;
  const float* mrow = mask + b*Sq;

  for (int kt = 0; kt < 8; kt++){
    __syncthreads();
    {
      const size_t krow = (size_t)(b*Sq + kt*64 + l) * 2304 + 768 + h*DHq;
      #pragma unroll
      for (int i = 0; i < 2; i++){
        const int ch = w + i*4;
        *(u32x4*)&Kh[l][ch*8] = *(const u32x4*)(qkvH + krow + ch*8);
        *(u32x4*)&Kl[l][ch*8] = *(const u32x4*)(qkvL + krow + ch*8);
      }
      const size_t vrow = krow + 768 + w*16;
      f16x8 v0 = __builtin_bit_cast(f16x8, *(const u32x4*)(qkvH + vrow));
      f16x8 v1 = __builtin_bit_cast(f16x8, *(const u32x4*)(qkvH + vrow + 8));
      f16x8 u0 = __builtin_bit_cast(f16x8, *(const u32x4*)(qkvL + vrow));
      f16x8 u1 = __builtin_bit_cast(f16x8, *(const u32x4*)(qkvL + vrow + 8));
      #pragma unroll
      for (int i = 0; i < 8; i++){
        Vh[w*16 + i][l] = v0[i]; Vh[w*16 + 8 + i][l] = v1[i];
        Vl[w*16 + i][l] = u0[i]; Vl[w*16 + 8 + i][l] = u1[i];
      }
      if (tid < 64) msk[tid] = mrow[kt*64 + tid] + 6.9314718055994531f; // + ln(1024)
    }
    __syncthreads();

    f32x16 sacc[2];
    #pragma unroll
    for (int mt = 0; mt < 2; mt++)
      #pragma unroll
      for (int i = 0; i < 16; i++) sacc[mt][i] = 0.f;
    #pragma unroll
    for (int mt = 0; mt < 2; mt++){
      #pragma unroll
      for (int c = 0; c < 4; c++){
        f16x8 kh = __builtin_bit_cast(f16x8, *(const u32x4*)&Kh[mt*32 + l31][c*16 + g5*8]);
        f16x8 kl = __builtin_bit_cast(f16x8, *(const u32x4*)&Kl[mt*32 + l31][c*16 + g5*8]);
        f16x8 qh = __builtin_bit_cast(f16x8, qfh[c]);
        f16x8 ql = __builtin_bit_cast(f16x8, qfl[c]);
        sacc[mt] = __builtin_amdgcn_mfma_f32_32x32x16_f16(kh, qh, sacc[mt], 0, 0, 0);
        sacc[mt] = __builtin_amdgcn_mfma_f32_32x32x16_f16(kh, ql, sacc[mt], 0, 0, 0);
        sacc[mt] = __builtin_amdgcn_mfma_f32_32x32x16_f16(kl, qh, sacc[mt], 0, 0, 0);
      }
    }

    unsigned int hP[2][4][2], lP[2][4][2];
    #pragma unroll
    for (int mt = 0; mt < 2; mt++){
      #pragma unroll
      for (int m = 0; m < 4; m++){
        f32x4 mk = *(const f32x4*)&msk[mt*32 + m*8 + g5*4];
        float p0 = __expf(fmaf(sacc[mt][4*m+0], SC, mk[0]));
        float p1 = __expf(fmaf(sacc[mt][4*m+1], SC, mk[1]));
        float p2 = __expf(fmaf(sacc[mt][4*m+2], SC, mk[2]));
        float p3 = __expf(fmaf(sacc[mt][4*m+3], SC, mk[3]));
        rsl += (p0 + p1) + (p2 + p3);
        f16x2 h0 = cvt_pk(p0, p1);
        f16x2 h1 = cvt_pk(p2, p3);
        f16x2 e0, e1;
        e0[0] = (_Float16)(p0 - (float)h0[0]); e0[1] = (_Float16)(p1 - (float)h0[1]);
        e1[0] = (_Float16)(p2 - (float)h1[0]); e1[1] = (_Float16)(p3 - (float)h1[1]);
        hP[mt][m][0] = __builtin_bit_cast(unsigned int, h0);
        hP[mt][m][1] = __builtin_bit_cast(unsigned int, h1);
        lP[mt][m][0] = __builtin_bit_cast(unsigned int, e0);
        lP[mt][m][1] = __builtin_bit_cast(unsigned int, e1);
      }
    }

    #pragma unroll
    for (int mt = 0; mt < 2; mt++){
      #pragma unroll
      for (int cc = 0; cc < 2; cc++){
        i32x2 sh0 = pl32swap(hP[mt][2*cc][0], hP[mt][2*cc+1][0]);
        i32x2 sh1 = pl32swap(hP[mt][2*cc][1], hP[mt][2*cc+1][1]);
        i32x2 sl0 = pl32swap(lP[mt][2*cc][0], lP[mt][2*cc+1][0]);
        i32x2 sl1 = pl32swap(lP[mt][2*cc][1], lP[mt][2*cc+1][1]);
        u32x4 pah = (u32x4){(unsigned)sh0[0], (unsigned)sh1[0], (unsigned)sh0[1], (unsigned)sh1[1]};
        u32x4 pal = (u32x4){(unsigned)sl0[0], (unsigned)sl1[0], (unsigned)sl0[1], (unsigned)sl1[1]};
        f16x8 ph = __builtin_bit_cast(f16x8, pah);
        f16x8 pe = __builtin_bit_cast(f16x8, pal);
        const int kof = (mt*2 + cc)*16 + g5*8;
        #pragma unroll
        for (int nt = 0; nt < 2; nt++){
          f16x8 vh = __builtin_bit_cast(f16x8, *(const u32x4*)&Vh[nt*32 + l31][kof]);
          f16x8 vl = __builtin_bit_cast(f16x8, *(const u32x4*)&Vl[nt*32 + l31][kof]);
          oacc[nt] = __builtin_amdgcn_mfma_f32_32x32x16_f16(ph, vh, oacc[nt], 0, 0, 0);
          oacc[nt] = __builtin_amdgcn_mfma_f32_32x32x16_f16(ph, vl, oacc[nt], 0, 0, 0);
          oacc[nt] = __builtin_amdgcn_mfma_f32_32x32x16_f16(pe, vh, oacc[nt], 0, 0, 0);
        }
      }
    }
  }

  {
    unsigned int rb = __builtin_bit_cast(unsigned int, rsl);
    i32x2 sw = pl32swap(rb, rb);
    float partner = __builtin_bit_cast(float, (l >= 32) ? sw[0] : sw[1]);
    float tot = rsl + partner;
    if (l < 32) rsi[w][l31] = 1.0f / tot;
  }
  __syncthreads();

  const size_t obase = (size_t)(b*Sq + qb*128 + w*32);
  #pragma unroll
  for (int nt = 0; nt < 2; nt++){
    const int col = h*DHq + nt*32 + l31;
    #pragma unroll
    for (int r = 0; r < 16; r++){
      const int q = (r&3) + 8*(r>>2) + 4*g5;
      const float v = oacc[nt][r] * rsi[w][q];
      const _Float16 hi = (_Float16)v;
      const size_t off = (obase + q)*Dq + col;
      ctxH[off] = hi;
      ctxL[off] = (_Float16)(v - (float)hi);
    }
  }
}

// ---------------- transpose + f32->bf16 (FFN weights -> [N][K] bf16) ----------------
__global__ void transpose_bf16_k(const float* __restrict__ src, unsigned short* __restrict__ dst,
                                 int K, int N)
{
  __shared__ float t[64][65];
  const int tid = threadIdx.x;
  const size_t mo = (size_t)blockIdx.z * K * N;
  const int k0 = blockIdx.y * 64, n0 = blockIdx.x * 64;
  const int r = tid >> 2, c0 = (tid & 3) * 16;
  const float* sp = src + mo + (size_t)(k0 + r) * N + n0 + c0;
  #pragma unroll
  for (int cc = 0; cc < 16; cc += 4){
    f32x4 v = *(const f32x4*)(sp + cc);
    t[r][c0+cc] = v[0]; t[r][c0+cc+1] = v[1]; t[r][c0+cc+2] = v[2]; t[r][c0+cc+3] = v[3];
  }
  __syncthreads();
  unsigned short* dp = dst + mo + (size_t)(n0 + r) * K + k0 + c0;
  u32x4 h0, h1v;
  #pragma unroll
  for (int i = 0; i < 4; i++) h0[i]  = pk2(t[c0+2*i  ][r], t[c0+2*i+1][r]);
  #pragma unroll
  for (int i = 0; i < 4; i++) h1v[i] = pk2(t[c0+8+2*i][r], t[c0+9+2*i][r]);
  *(u32x4*)(dp)     = h0;
  *(u32x4*)(dp + 8) = h1v;
}

// ------- bf16 MFMA GEMM (FFN path), all-DMA double-buffered staging -------
// MT: 128 or 64 row tile. GATHER: A rows via tok_idx.
// OMODE: 0 bf16 store; 1 f32 accumulate (Cf += v); 2 f32 scatter add gate*(v) via tok_idx
template<int MT, bool GATHER, int OMODE, bool GELU_, bool GROUPED>
__global__ __launch_bounds__(256,2) void gemm_bf16_k(
    const unsigned short* __restrict__ A, const unsigned short* __restrict__ BT,
    const float* __restrict__ bias, float* __restrict__ Cf, unsigned short* __restrict__ Cb,
    int N, int K,
    const int* __restrict__ tile_g, const int* __restrict__ tile_r0,
    const int* __restrict__ grp_off, const int* __restrict__ n_tiles,
    const int* __restrict__ tok_idx, const float* __restrict__ gate_s,
    size_t bstride, int bias_stride)
{
  constexpr int MI = MT / 32;            // acc rows per wave
  constexpr int AI = MT / 64;            // A DMA instrs per wave
  __shared__ unsigned short As[2][MT][32];
  __shared__ unsigned short Bs[2][128][32];
  const int tid = threadIdx.x;
  const int lane = tid & 63, wave = tid >> 6;
  const int wm = wave >> 1, wn = wave & 1;
  int col0, row0, gend = 1 << 30, g = 0;
  if constexpr (GROUPED){
    const int gx = gridDim.x;
    const int nb = gx * gridDim.y;
    const int bid = blockIdx.y * gx + blockIdx.x;
    int lb = bid;
    if ((nb & 7) == 0) lb = (bid & 7) * (nb >> 3) + (bid >> 3);
    const int t = lb / gx;
    col0 = (lb - t * gx) * 128;
    if (t >= *n_tiles) return;
    g = tile_g[t];
    row0 = grp_off[g] + tile_r0[t];
    gend = grp_off[g+1];
  } else {
    int bx, by; swz2d(bx, by);
    row0 = by * MT;
    col0 = bx * 128;
  }
  const unsigned short* Bp = BT + (size_t)g * bstride;
  const float* bp = bias + (size_t)g * bias_stride;

  const int lr = lane >> 2, lk8 = (lane & 3) * 8;
  const unsigned short* pB[2];
  #pragma unroll
  for (int j = 0; j < 2; j++){
    const int ib = wave*2 + j;
    pB[j] = Bp + (size_t)(col0 + ib*16 + lr)*K + lk8;
  }
  auto stageB = [&](int c, int kk){
    gl_lds16(pB[0] + kk, &Bs[0][0][0] + c*4096 + (wave*2+0)*512);
    gl_lds16(pB[1] + kk, &Bs[0][0][0] + c*4096 + (wave*2+1)*512);
  };
  const unsigned short* pA[AI];
  #pragma unroll
  for (int j = 0; j < AI; j++){
    int r = row0 + (wave*AI + j)*16 + lr;
    if constexpr (GROUPED) r = (r < gend - 1) ? r : (gend - 1);
    if constexpr (GATHER) r = tok_idx[r];
    pA[j] = A + (size_t)r*K + lk8;
  }
  auto stageA = [&](int c, int kk){
    #pragma unroll
    for (int j = 0; j < AI; j++)
      gl_lds16(pA[j] + kk, &As[0][0][0] + c*(MT*32) + (wave*AI + j)*512);
  };

  f32x4 acc[MI][4];
  #pragma unroll
  for (int mi=0;mi<MI;mi++)
    #pragma unroll
    for (int ni=0;ni<4;ni++) acc[mi][ni] = (f32x4){0.f,0.f,0.f,0.f};

  const int nt = K >> 5;
  stageA(0, 0);
  stageB(0, 0);

  int cur = 0;
  for (int t = 0; t < nt; t++){
    __syncthreads();                      // tile t ready
    const int k1 = (t + 1) << 5;
    if (t + 1 < nt){
      stageA(cur ^ 1, k1);
      stageB(cur ^ 1, k1);
    }
    bf16x8 af[MI], bfr[4];
    #pragma unroll
    for (int mi=0;mi<MI;mi++){
      u32x4 tt = *(const u32x4*)&As[cur][wm*(MT/2) + mi*16 + (lane&15)][8*(lane>>4)];
      af[mi] = __builtin_bit_cast(bf16x8, tt);
    }
    #pragma unroll
    for (int ni=0;ni<4;ni++){
      u32x4 tt = *(const u32x4*)&Bs[cur][wn*64 + ni*16 + (lane&15)][8*(lane>>4)];
      bfr[ni] = __builtin_bit_cast(bf16x8, tt);
    }
    #pragma unroll
    for (int mi=0;mi<MI;mi++)
      #pragma unroll
      for (int ni=0;ni<4;ni++)
        acc[mi][ni] = __builtin_amdgcn_mfma_f32_16x16x32_bf16(af[mi], bfr[ni], acc[mi][ni], 0, 0, 0);
    cur ^= 1;
  }

  const int erow = 4*(lane >> 4);
  const int ecol = lane & 15;
  #pragma unroll
  for (int mi=0;mi<MI;mi++)
    #pragma unroll
    for (int ni=0;ni<4;ni++){
      const int c = col0 + wn*64 + ni*16 + ecol;
      const float bb = bp[c];
      #pragma unroll
      for (int r=0;r<4;r++){
        const int R = row0 + wm*(MT/2) + mi*16 + erow + r;
        if (GROUPED && R >= gend) continue;
        float v = acc[mi][ni][r] + bb;
        if (GELU_) v = 0.5f*v*(1.0f + erff(v*0.70710678118654752f));
        if constexpr (OMODE == 0){
          Cb[(size_t)R*N + c] = f2bf(v);
        } else if constexpr (OMODE == 1){
          Cf[(size_t)R*N + c] += v;
        } else {
          const int tok = tok_idx[R];
          const float gt = gate_s[R];
          float* p = Cf + (size_t)tok*N + c;
          *p += gt*v;
        }
      }
    }
}

// ---------------- token-level switch router (f32, one wave/token) ----------------
__global__ void token_router_k(const float* __restrict__ att, const int* __restrict__ sel,
    const float* __restrict__ sww, const float* __restrict__ swb,
    int* __restrict__ grp, float* __restrict__ gate, int* __restrict__ grp_cnt)
{
  const int t = blockIdx.x*4 + (threadIdx.x >> 6);
  const int lane = threadIdx.x & 63;
  const int e = sel[t >> 9];
  const float* x = att + (size_t)t * Dq;
  const float* w = sww + (size_t)e * Dq * 4;
  float a0=0.f, a1=0.f, a2=0.f, a3=0.f;
  #pragma unroll 4
  for (int i = 0; i < 12; i++){
    const int d = lane + i*64;
    const float xv = x[d];
    f32x4 wv = *(const f32x4*)&w[d*4];
    a0 += xv*wv[0]; a1 += xv*wv[1]; a2 += xv*wv[2]; a3 += xv*wv[3];
  }
  #pragma unroll
  for (int off = 32; off; off >>= 1){
    a0 += __shfl_xor(a0, off); a1 += __shfl_xor(a1, off);
    a2 += __shfl_xor(a2, off); a3 += __shfl_xor(a3, off);
  }
  if (lane == 0){
    const float l0 = a0 + swb[e*4+0], l1 = a1 + swb[e*4+1];
    const float l2 = a2 + swb[e*4+2], l3 = a3 + swb[e*4+3];
    const float mx = fmaxf(fmaxf(l0,l1), fmaxf(l2,l3));
    const float p0 = expf(l0-mx), p1 = expf(l1-mx), p2 = expf(l2-mx), p3 = expf(l3-mx);
    const float ssum = p0+p1+p2+p3;
    int am = 0; float bv = p0;
    if (p1 > bv){ bv=p1; am=1; }
    if (p2 > bv){ bv=p2; am=2; }
    if (p3 > bv){ bv=p3; am=3; }
    grp[t] = e*4 + am;
    gate[t] = bv/ssum;
    atomicAdd(&grp_cnt[e*4 + am], 1);
  }
}

__global__ void build_offsets_k(const int* __restrict__ grp_cnt, int* __restrict__ grp_off,
    int* __restrict__ tg128, int* __restrict__ tr128, int* __restrict__ nt128,
    int* __restrict__ tg64, int* __restrict__ tr64, int* __restrict__ nt64)
{
  int off = 0, n1 = 0, n2 = 0;
  for (int g = 0; g < 16; g++){
    grp_off[g] = off;
    const int c = grp_cnt[g];
    for (int r0 = 0; r0 < c; r0 += 128){ tg128[n1] = g; tr128[n1] = r0; n1++; }
    for (int r0 = 0; r0 < c; r0 += 64){  tg64[n2]  = g; tr64[n2]  = r0; n2++; }
    off += c;
  }
  grp_off[16] = off;
  *nt128 = n1; *nt64 = n2;
}

__global__ void scatter_k(const int* __restrict__ grp, const float* __restrict__ gate,
    const int* __restrict__ grp_off, int* __restrict__ fill,
    int* __restrict__ tok_idx, float* __restrict__ gate_s)
{
  const int t = blockIdx.x*256 + threadIdx.x;
  const int g = grp[t];
  const int pos = grp_off[g] + atomicAdd(&fill[g], 1);
  tok_idx[pos] = t;
  gate_s[pos] = gate[t];
}

// ---------------- final LayerNorm (att already holds att+ffn) ----------------
__global__ __launch_bounds__(256) void final_ln_k(const float* __restrict__ att,
    const float* __restrict__ lg, const float* __restrict__ lb, float* __restrict__ out)
{
  const int row = blockIdx.x, tid = threadIdx.x;
  const float* a = att + (size_t)row * Dq;
  float x[3];
  #pragma unroll
  for (int i = 0; i < 3; i++) x[i] = a[tid + 256*i];
  __shared__ float red[256];
  red[tid] = x[0] + x[1] + x[2];
  __syncthreads();
  for (int st = 128; st; st >>= 1){
    if (tid < st) red[tid] += red[tid + st];
    __syncthreads();
  }
  const float mu = red[0] * (1.0f/768.0f);
  __syncthreads();
  const float d0 = x[0]-mu, d1 = x[1]-mu, d2 = x[2]-mu;
  red[tid] = d0*d0 + d1*d1 + d2*d2;
  __syncthreads();
  for (int st = 128; st; st >>= 1){
    if (tid < st) red[tid] += red[tid + st];
    __syncthreads();
  }
  const float inv = 1.0f/sqrtf(red[0]*(1.0f/768.0f) + 1e-12f);
  #pragma unroll
  for (int i = 0; i < 3; i++){
    const int col = tid + 256*i;
    out[(size_t)row*Dq + col] = (x[i]-mu)*inv*lg[col] + lb[col];
  }
}

// ======================= launch =======================
extern "C" void kernel_launch(void* const* d_in, const int* in_sizes, int n_in,
                              void* d_out, int out_size, void* d_ws, size_t ws_size,
                              hipStream_t stream)
{
  (void)in_sizes; (void)n_in; (void)out_size; (void)ws_size;
  const float* hs    = (const float*)d_in[0];
  const float* amask = (const float*)d_in[1];
  const float* sw_enc_w = (const float*)d_in[3];
  const float* sw_enc_b = (const float*)d_in[4];
  const float* sw_w  = (const float*)d_in[5];
  const float* sw_b  = (const float*)d_in[6];
  const float* ca_wq = (const float*)d_in[7];
  const float* ca_bq = (const float*)d_in[8];
  const float* ca_wk = (const float*)d_in[9];
  const float* ca_bk = (const float*)d_in[10];
  const float* ca_wv = (const float*)d_in[11];
  const float* ca_bv = (const float*)d_in[12];
  const float* ca_wo = (const float*)d_in[13];
  const float* ca_bo = (const float*)d_in[14];
  const float* ua_wq = (const float*)d_in[15];
  const float* ua_bq = (const float*)d_in[16];
  const float* ua_wk = (const float*)d_in[17];
  const float* ua_bk = (const float*)d_in[18];
  const float* ua_wv = (const float*)d_in[19];
  const float* ua_bv = (const float*)d_in[20];
  const float* ua_wo = (const float*)d_in[21];
  const float* ua_bo = (const float*)d_in[22];
  const float* cf_w1 = (const float*)d_in[23];
  const float* cf_b1 = (const float*)d_in[24];
  const float* cf_w2 = (const float*)d_in[25];
  const float* cf_b2 = (const float*)d_in[26];
  const float* uf_sw_w = (const float*)d_in[27];
  const float* uf_sw_b = (const float*)d_in[28];
  const float* uf_w1 = (const float*)d_in[29];
  const float* uf_b1 = (const float*)d_in[30];
  const float* uf_w2 = (const float*)d_in[31];
  const float* uf_b2 = (const float*)d_in[32];
  const float* ln_g  = (const float*)d_in[33];
  const float* ln_b  = (const float*)d_in[34];
  float* out = (float*)d_out;

  char* W = (char*)d_ws;
  // control block
  int*   sel     = (int*)(W + 0);
  float* pm      = (float*)(W + 64);
  int*   grp_cnt = (int*)(W + 128);
  int*   fill    = (int*)(W + 192);
  int*   ntile   = (int*)(W + 256);
  int*   ntile64 = (int*)(W + 320);
  int*   grp_off = (int*)(W + 512);
  int*   tile_g  = (int*)(W + 1024);
  int*   tile_r  = (int*)(W + 2048);
  int*   tile_g64= (int*)(W + 3072);
  int*   tile_r64= (int*)(W + 4096);

  float* att = (float*)(W + 8192);                        // [8192][768] f32, holds att then att+ffn
  unsigned short* attb = (unsigned short*)(W + 25174016); // [8192][768] bf16 snapshot, end 37,756,928
  const size_t X = 50339840;
  _Float16* hsH  = (_Float16*)(W + X);                 // 12,582,912
  _Float16* hsL  = (_Float16*)(W + X + 12582912);
  _Float16* qkvH = (_Float16*)(W + X + 25165824);      // 37,748,736
  _Float16* qkvL = (_Float16*)(W + X + 62914560);      // end X+100663296
  _Float16* ctxH = (_Float16*)(W + X + 100663296);     // 12,582,912
  _Float16* ctxL = (_Float16*)(W + X + 113246208);     // end X+125829120
  _Float16* wqkv_cH = (_Float16*)(W + X + 125829120);  // 3,538,944
  _Float16* wqkv_cL = (_Float16*)(W + X + 129368064);
  _Float16* wqkv_uH = (_Float16*)(W + X + 132907008);  // 14,155,776
  _Float16* wqkv_uL = (_Float16*)(W + X + 147062784);
  _Float16* wo_cH   = (_Float16*)(W + X + 161218560);  // 1,179,648
  _Float16* wo_cL   = (_Float16*)(W + X + 162398208);
  _Float16* wo_uH   = (_Float16*)(W + X + 163577856);  // 4,718,592
  _Float16* wo_uL   = (_Float16*)(W + X + 168296448);  // end X+173015040
  float* qkvb_c = (float*)(W + X + 173015040);         // 9,216
  float* qkvb_u = (float*)(W + X + 173024256);         // 36,864
  float* partb  = (float*)(W + X + 173061120);         // 196,608

  // phase B (after attention) reuses phase-A scratch:
  unsigned short* w1T = (unsigned short*)(W + X);              // 80,216,064
  unsigned short* w2T = (unsigned short*)(W + X + 80216064);   // end X+160432128
  unsigned short* h1  = (unsigned short*)(W + X + 160432128);  // 50,331,648
  int*   grp     = (int*)(W + 261103616);
  float* gate    = (float*)(W + 261136384);
  int*   tok_idx = (int*)(W + 261169152);
  float* gate_s  = (float*)(W + 261201920);

  hipMemsetAsync(W, 0, 512, stream);

  // ---- sequence router (exact f32) ----
  pooled_partial_k<<<dim3(Bq,3,4),256,0,stream>>>(hs, partb);
  router_seq_k<<<Bq,128,0,stream>>>(partb, sw_enc_w, sw_enc_b, sw_w, sw_b, sel, pm);

  // ---- prepare split-f16 operands ----
  split_f16_k<<<6144,256,0,stream>>>(hs, hsH, hsL, NTq*Dq/4);
  transpose_f16s_k<<<dim3(12,12,1),256,0,stream>>>(ca_wq, wqkv_cH, wqkv_cL, Dq, Dq, 0, 0, 0);
  transpose_f16s_k<<<dim3(12,12,1),256,0,stream>>>(ca_wk, wqkv_cH, wqkv_cL, Dq, Dq, 0, 0, 768);
  transpose_f16s_k<<<dim3(12,12,1),256,0,stream>>>(ca_wv, wqkv_cH, wqkv_cL, Dq, Dq, 0, 0, 1536);
  transpose_f16s_k<<<dim3(12,12,4),256,0,stream>>>(ua_wq, wqkv_uH, wqkv_uL, Dq, Dq, (long)Dq*Dq, (long)2304*768, 0);
  transpose_f16s_k<<<dim3(12,12,4),256,0,stream>>>(ua_wk, wqkv_uH, wqkv_uL, Dq, Dq, (long)Dq*Dq, (long)2304*768, 768);
  transpose_f16s_k<<<dim3(12,12,4),256,0,stream>>>(ua_wv, wqkv_uH, wqkv_uL, Dq, Dq, (long)Dq*Dq, (long)2304*768, 1536);
  transpose_f16s_k<<<dim3(12,12,1),256,0,stream>>>(ca_wo, wo_cH, wo_cL, Dq, Dq, 0, 0, 0);
  transpose_f16s_k<<<dim3(12,12,4),256,0,stream>>>(ua_wo, wo_uH, wo_uL, Dq, Dq, (long)Dq*Dq, (long)Dq*Dq, 0);
  concat_bias3_k<<<dim3(3,1),256,0,stream>>>(ca_bq, ca_bk, ca_bv, qkvb_c, 0);
  concat_bias3_k<<<dim3(3,4),256,0,stream>>>(ua_bq, ua_bk, ua_bv, qkvb_u, 768);

  // ---- common attention ----
  gemm_f16s_k<128,0,2><<<dim3(18,64),256,0,stream>>>(hsH, hsL, wqkv_cH, wqkv_cL, qkvb_c,
      nullptr, qkvH, qkvL, nullptr, 2304, Dq, 0, 0, nullptr, nullptr);
  attn_mfma_k<<<dim3(4,Hq,Bq),256,0,stream>>>(qkvH, qkvL, amask, ctxH, ctxL);
  gemm_f16s_k<64,0,0><<<dim3(6,128),256,0,stream>>>(ctxH, ctxL, wo_cH, wo_cL, ca_bo,
      att, nullptr, nullptr, attb, Dq, Dq, 0, 0, nullptr, nullptr);

  // ---- unique attention (selected expert), att += pm * result ----
  gemm_f16s_k<128,1,2><<<dim3(18,64),256,0,stream>>>(hsH, hsL, wqkv_uH, wqkv_uL, qkvb_u,
      nullptr, qkvH, qkvL, nullptr, 2304, Dq, (long)2304*768, 2304, sel, nullptr);
  attn_mfma_k<<<dim3(4,Hq,Bq),256,0,stream>>>(qkvH, qkvL, amask, ctxH, ctxL);
  gemm_f16s_k<64,1,1><<<dim3(6,128),256,0,stream>>>(ctxH, ctxL, wo_uH, wo_uL, ua_bo,
      att, nullptr, nullptr, attb, Dq, Dq, (long)Dq*Dq, Dq, sel, pm);

  // ---- token routing on pristine f32 att (before in-place FFN accumulate) ----
  token_router_k<<<2048,256,0,stream>>>(att, sel, uf_sw_w, uf_sw_b, grp, gate, grp_cnt);
  build_offsets_k<<<1,1,0,stream>>>(grp_cnt, grp_off, tile_g, tile_r, ntile, tile_g64, tile_r64, ntile64);
  scatter_k<<<32,256,0,stream>>>(grp, gate, grp_off, fill, tok_idx, gate_s);

  // ---- FFN weights -> transposed bf16 (phase-A scratch now free) ----
  transpose_bf16_k<<<dim3(48,12,1), 256,0,stream>>>(cf_w1, w1T, Dq, Fq);
  transpose_bf16_k<<<dim3(48,12,16),256,0,stream>>>(uf_w1, w1T + 2359296, Dq, Fq);
  transpose_bf16_k<<<dim3(12,48,1), 256,0,stream>>>(cf_w2, w2T, Fq, Dq);
  transpose_bf16_k<<<dim3(12,48,16),256,0,stream>>>(uf_w2, w2T + 2359296, Fq, Dq);

  // ---- common FFN (bf16 MFMA, all-DMA) ----
  gemm_bf16_k<128,false,0,true,false><<<dim3(24,64),256,0,stream>>>(attb, w1T, cf_b1, nullptr, h1,
      Fq, Dq, nullptr,nullptr,nullptr,nullptr,nullptr,nullptr, (size_t)0, 0);
  gemm_bf16_k<64,false,1,false,false><<<dim3(6,128),256,0,stream>>>(h1, w2T, cf_b2, att, nullptr,
      Dq, Fq, nullptr,nullptr,nullptr,nullptr,nullptr,nullptr, (size_t)0, 0);

  // ---- unique FFN (grouped, top-1 inner expert, gated scatter-add into att) ----
  gemm_bf16_k<128,true,0,true,true><<<dim3(24,80),256,0,stream>>>(attb, w1T + 2359296, uf_b1, nullptr, h1,
      Fq, Dq, tile_g, tile_r, grp_off, ntile, tok_idx, gate_s, (size_t)2359296, Fq);
  gemm_bf16_k<64,false,2,false,true><<<dim3(6,144),256,0,stream>>>(h1, w2T + 2359296, uf_b2, att, nullptr,
      Dq, Fq, tile_g64, tile_r64, grp_off, ntile64, tok_idx, gate_s, (size_t)2359296, Dq);

  // ---- LayerNorm (att holds residual+ffn) ----
  final_ln_k<<<NTq,256,0,stream>>>(att, ln_g, ln_b, out);
}

// Round 11
// 1126.306 us; speedup vs baseline: 1.0424x; 1.0056x over previous
//
#include <hip/hip_runtime.h>
#include <cstdint>
#include <cstddef>

#define Bq  16
#define Sq  512
#define Dq  768
#define Hq  12
#define DHq 64
#define Fq  3072
#define SWq 128
#define NTq 8192

typedef float        f32x4  __attribute__((ext_vector_type(4)));
typedef float        f32x16 __attribute__((ext_vector_type(16)));
typedef unsigned int u32x4  __attribute__((ext_vector_type(4)));
typedef __bf16       bf16x8 __attribute__((ext_vector_type(8)));
typedef _Float16     f16x8  __attribute__((ext_vector_type(8)));
typedef _Float16     f16x4  __attribute__((ext_vector_type(4)));
typedef _Float16     f16x2  __attribute__((ext_vector_type(2)));
typedef int          i32x2  __attribute__((ext_vector_type(2)));

__device__ __forceinline__ unsigned short f2bf(float f){
  unsigned int u = __builtin_bit_cast(unsigned int, f);
  u = (u + 0x7fffu + ((u >> 16) & 1u)) >> 16;
  return (unsigned short)u;
}
__device__ __forceinline__ unsigned int pk2(float a, float b){
  return (unsigned int)f2bf(a) | ((unsigned int)f2bf(b) << 16);
}
__device__ __forceinline__ i32x2 pl32swap(unsigned int a, unsigned int b){
  return __builtin_amdgcn_permlane32_swap((int)a, (int)b, false, false);
}
__device__ __forceinline__ f16x2 cvt_pk(float a, float b){
  return __builtin_bit_cast(f16x2, __builtin_amdgcn_cvt_pkrtz(a, b));
}

// async global->LDS DMA, 16B per lane. LDS dest = wave-uniform base + lane*16.
typedef __attribute__((address_space(1))) void vg_t;
typedef __attribute__((address_space(3))) void vl_t;
__device__ __forceinline__ void gl_lds16(const void* g, void* l){
  __builtin_amdgcn_global_load_lds((vg_t*)g, (vl_t*)l, 16, 0, 0);
}

// Band-supertile + XCD-aware bijective block remap (non-grouped GEMMs).
__device__ __forceinline__ void swz2d(int &bx, int &by){
  const int gx = gridDim.x, gy = gridDim.y;
  const int nb = gx * gy;
  const int bid = blockIdx.y * gx + blockIdx.x;
  if (((nb & 7) == 0) && ((gy & 7) == 0)){
    const int chunk = nb >> 3;
    const int lb = (bid & 7) * chunk + (bid >> 3);
    const int bw = gx << 3;              // blocks per band
    const int band = lb / bw;
    const int wn = lb - band * bw;
    bx = wn >> 3;
    by = (band << 3) + (wn & 7);
  } else {
    bx = blockIdx.x; by = blockIdx.y;
  }
}

// ---------------- pooled partial sums (seq router input) ----------------
__global__ void pooled_partial_k(const float* __restrict__ x, float* __restrict__ part){
  const int b = blockIdx.x, dc = blockIdx.y, z = blockIdx.z;
  const int d = dc*256 + threadIdx.x;
  const float* p = x + (size_t)b*Sq*Dq + (size_t)z*128*Dq + d;
  float s = 0.f;
  #pragma unroll 4
  for (int i = 0; i < 128; i++) s += p[(size_t)i*Dq];
  part[((size_t)z*Bq + b)*Dq + d] = s;
}

// ---------------- sequence-level router (exact f32) ----------------
__global__ void router_seq_k(const float* __restrict__ part,
    const float* __restrict__ ew, const float* __restrict__ eb,
    const float* __restrict__ sw, const float* __restrict__ sb,
    int* __restrict__ sel, float* __restrict__ pm)
{
  const int b = blockIdx.x, j = threadIdx.x;   // 128 threads
  __shared__ float h[SWq];
  __shared__ float pl[Dq];
  #pragma unroll
  for (int i = 0; i < 6; i++){
    int d = j + i*128;
    float s = part[(size_t)(0*Bq+b)*Dq + d] + part[(size_t)(1*Bq+b)*Dq + d]
            + part[(size_t)(2*Bq+b)*Dq + d] + part[(size_t)(3*Bq+b)*Dq + d];
    pl[d] = s * (1.0f/512.0f);
  }
  __syncthreads();
  float a = eb[j];
  for (int d = 0; d < Dq; d++) a += pl[d] * ew[d*SWq + j];
  h[j] = a;
  __syncthreads();
  if (j == 0){
    float lg[4];
    for (int e = 0; e < 4; e++){
      float t = sb[e];
      for (int k = 0; k < SWq; k++) t += h[k] * sw[k*4 + e];
      lg[e] = t;
    }
    float mx = fmaxf(fmaxf(lg[0],lg[1]), fmaxf(lg[2],lg[3]));
    float p[4], ssum = 0.f;
    for (int e = 0; e < 4; e++){ p[e] = expf(lg[e]-mx); ssum += p[e]; }
    int am = 0; float bv = p[0];
    for (int e = 1; e < 4; e++) if (p[e] > bv){ bv = p[e]; am = e; }
    sel[b] = am; pm[b] = bv/ssum;
  }
}

// ---------------- f32 -> f16 hi/lo split (x1024 scale) ----------------
__global__ void split_f16_k(const float* __restrict__ x, _Float16* __restrict__ hh,
                            _Float16* __restrict__ ll, int n4){
  const int i = blockIdx.x*256 + threadIdx.x;
  if (i >= n4) return;
  f32x4 v = ((const f32x4*)x)[i];
  f16x4 vh, vl;
  #pragma unroll
  for (int j = 0; j < 4; j++){
    float s = v[j] * 1024.0f;
    _Float16 a = (_Float16)s;
    vh[j] = a;
    vl[j] = (_Float16)(s - (float)a);
  }
  ((f16x4*)hh)[i] = vh;
  ((f16x4*)ll)[i] = vl;
}

// ------- weight transpose + f16 hi/lo split: src [K][N] -> dst [N][K] x1024 -------
__global__ void transpose_f16s_k(const float* __restrict__ src,
    _Float16* __restrict__ dH, _Float16* __restrict__ dL,
    int K, int N, long srcStride, long dstStride, int rowOff)
{
  __shared__ float t[64][65];
  const int tid = threadIdx.x;
  const size_t so = (size_t)blockIdx.z * srcStride;
  const size_t dof = (size_t)blockIdx.z * dstStride;
  const int k0 = blockIdx.y * 64, n0 = blockIdx.x * 64;
  const int r = tid >> 2, c0 = (tid & 3) * 16;
  const float* sp = src + so + (size_t)(k0 + r) * N + n0 + c0;
  #pragma unroll
  for (int cc = 0; cc < 16; cc += 4){
    f32x4 v = *(const f32x4*)(sp + cc);
    t[r][c0+cc] = v[0]; t[r][c0+cc+1] = v[1]; t[r][c0+cc+2] = v[2]; t[r][c0+cc+3] = v[3];
  }
  __syncthreads();
  _Float16* ph = dH + dof + (size_t)(rowOff + n0 + r) * K + k0 + c0;
  _Float16* pl = dL + dof + (size_t)(rowOff + n0 + r) * K + k0 + c0;
  #pragma unroll
  for (int cc = 0; cc < 16; cc += 4){
    f16x4 vh, vl;
    #pragma unroll
    for (int j = 0; j < 4; j++){
      float s = t[c0+cc+j][r] * 1024.0f;
      _Float16 a = (_Float16)s;
      vh[j] = a; vl[j] = (_Float16)(s - (float)a);
    }
    *(f16x4*)(ph + cc) = vh;
    *(f16x4*)(pl + cc) = vl;
  }
}

// ---------------- concat q/k/v biases -> [E][2304] ----------------
__global__ void concat_bias3_k(const float* __restrict__ bq, const float* __restrict__ bk,
    const float* __restrict__ bv, float* __restrict__ dst, int srcStride)
{
  const int e = blockIdx.y;
  const int i = blockIdx.x*256 + threadIdx.x;   // grid.x=3 -> i<768
  dst[(size_t)e*2304 + i]        = bq[(size_t)e*srcStride + i];
  dst[(size_t)e*2304 + 768 + i]  = bk[(size_t)e*srcStride + i];
  dst[(size_t)e*2304 + 1536 + i] = bv[(size_t)e*srcStride + i];
}

// ------- split-f16 3-term MFMA GEMM, single-buffered global_load_lds staging -------
// LDS tiles bank-deswizzled: LDS chunk (r, c) holds global chunk (r, c ^ ((r>>1)&3));
// DMA source is pre-swizzled per-lane, reads XOR the same key (rule #21 involution).
// MT: 128 or 64 row tile.
// OMODE: 0 C=v (+bf16 mirror Cb16); 1 C += pm*v (+bf16 mirror of new value); 2 split-f16 store
template<int MT, int BMODE, int OMODE>
__global__ __launch_bounds__(256,2) void gemm_f16s_k(
    const _Float16* __restrict__ AH, const _Float16* __restrict__ AL,
    const _Float16* __restrict__ BH, const _Float16* __restrict__ BL,
    const float* __restrict__ bias, float* __restrict__ C,
    _Float16* __restrict__ Ch, _Float16* __restrict__ Cl,
    unsigned short* __restrict__ Cb16,
    int N, int K, long estride, int bias_stride,
    const int* __restrict__ sel, const float* __restrict__ pm)
{
  constexpr int MI = MT / 32;      // m-frags per wave
  constexpr int AI = MT / 64;      // A DMA instrs per wave per H/L tile
  __shared__ _Float16 AsH[MT][32];
  __shared__ _Float16 AsL[MT][32];
  __shared__ _Float16 BsH[128][32];
  __shared__ _Float16 BsL[128][32];
  const int tid = threadIdx.x;
  const int lane = tid & 63, wave = tid >> 6;
  const int wm = wave >> 1, wn = wave & 1;
  int bx, by; swz2d(bx, by);
  const int row0 = by * MT, col0 = bx * 128;
  const _Float16* bh = BH; const _Float16* bl = BL; const float* bp = bias;
  float cs = 1.0f;
  if constexpr (BMODE == 1){
    const int e = sel[row0 >> 9];
    bh += (size_t)e * estride; bl += (size_t)e * estride;
    bp += (size_t)e * bias_stride;
  }
  if constexpr (OMODE == 1) cs = pm[row0 >> 9];

  // DMA source swizzle: lane j covers LDS-row lr=j>>2, LDS-chunk j&3; fetch global
  // chunk (j&3)^((lr>>1)&3) so LDS ends up holding the swizzled layout.
  const int lr = lane >> 2;
  const int lk = (((lane & 3) ^ ((lane >> 3) & 3)) * 8);
  const _Float16 *pAH[AI], *pAL[AI], *pBH[2], *pBL[2];
  _Float16 *lAH[AI], *lAL[AI], *lBH[2], *lBL[2];
  #pragma unroll
  for (int j = 0; j < AI; j++){
    const int ia = wave*AI + j;
    pAH[j] = AH + (size_t)(row0 + ia*16 + lr)*K + lk;
    pAL[j] = AL + (size_t)(row0 + ia*16 + lr)*K + lk;
    lAH[j] = &AsH[0][0] + ia*512;
    lAL[j] = &AsL[0][0] + ia*512;
  }
  #pragma unroll
  for (int j = 0; j < 2; j++){
    const int ib = wave*2 + j;
    pBH[j] = bh + (size_t)(col0 + ib*16 + lr)*K + lk;
    pBL[j] = bl + (size_t)(col0 + ib*16 + lr)*K + lk;
    lBH[j] = &BsH[0][0] + ib*512;
    lBL[j] = &BsL[0][0] + ib*512;
  }
  // fragment-read column (f16 elems), XOR-deswizzled: chunk = (lane>>4) ^ ((r>>1)&3),
  // (r>>1)&3 = ((lane&15)>>1)&3 = (lane>>1)&3  (mi*16, wm*MT/2 are 0 mod 8)
  const int fc = (((lane >> 4) ^ ((lane >> 1) & 3)) * 8);
  const int fr = lane & 15;

  f32x4 acc[MI][4];
  #pragma unroll
  for (int mi=0;mi<MI;mi++)
    #pragma unroll
    for (int ni=0;ni<4;ni++) acc[mi][ni] = (f32x4){0.f,0.f,0.f,0.f};

  for (int k0 = 0; k0 < K; k0 += 32){
    __syncthreads();
    #pragma unroll
    for (int j = 0; j < AI; j++){
      gl_lds16(pAH[j] + k0, lAH[j]);
      gl_lds16(pAL[j] + k0, lAL[j]);
    }
    #pragma unroll
    for (int j = 0; j < 2; j++){
      gl_lds16(pBH[j] + k0, lBH[j]);
      gl_lds16(pBL[j] + k0, lBL[j]);
    }
    __syncthreads();
    f16x8 fah[MI], fal[MI], fbh[4], fbl[4];
    #pragma unroll
    for (int mi=0;mi<MI;mi++){
      const int r = wm*(MT/2) + mi*16 + fr;
      fah[mi] = __builtin_bit_cast(f16x8, *(const u32x4*)&AsH[r][fc]);
      fal[mi] = __builtin_bit_cast(f16x8, *(const u32x4*)&AsL[r][fc]);
    }
    #pragma unroll
    for (int ni=0;ni<4;ni++){
      const int r = wn*64 + ni*16 + fr;
      fbh[ni] = __builtin_bit_cast(f16x8, *(const u32x4*)&BsH[r][fc]);
      fbl[ni] = __builtin_bit_cast(f16x8, *(const u32x4*)&BsL[r][fc]);
    }
    #pragma unroll
    for (int mi=0;mi<MI;mi++)
      #pragma unroll
      for (int ni=0;ni<4;ni++){
        acc[mi][ni] = __builtin_amdgcn_mfma_f32_16x16x32_f16(fah[mi], fbh[ni], acc[mi][ni], 0, 0, 0);
        acc[mi][ni] = __builtin_amdgcn_mfma_f32_16x16x32_f16(fah[mi], fbl[ni], acc[mi][ni], 0, 0, 0);
        acc[mi][ni] = __builtin_amdgcn_mfma_f32_16x16x32_f16(fal[mi], fbh[ni], acc[mi][ni], 0, 0, 0);
      }
  }

  const float INV = 1.0f/1048576.0f;   // undo 1024*1024 scaling (exact pow2)
  const int erow = 4*(lane >> 4);
  const int ecol = lane & 15;
  #pragma unroll
  for (int mi=0;mi<MI;mi++)
    #pragma unroll
    for (int ni=0;ni<4;ni++){
      const int c = col0 + wn*64 + ni*16 + ecol;
      const float bb = bp[c];
      #pragma unroll
      for (int r=0;r<4;r++){
        const int R = row0 + wm*(MT/2) + mi*16 + erow + r;
        const float v = acc[mi][ni][r]*INV + bb;
        if constexpr (OMODE == 0){
          C[(size_t)R*N + c] = v;
          Cb16[(size_t)R*N + c] = f2bf(v);
        } else if constexpr (OMODE == 1){
          const float val = C[(size_t)R*N + c] + cs*v;
          C[(size_t)R*N + c] = val;
          Cb16[(size_t)R*N + c] = f2bf(val);
        } else {
          const float vs = v * 1024.0f;
          const _Float16 hi = (_Float16)vs;
          Ch[(size_t)R*N + c] = hi;
          Cl[(size_t)R*N + c] = (_Float16)(vs - (float)hi);
        }
      }
    }
}

// ------- split-f16 MFMA attention (swapped-QK, in-register softmax) -------
__global__ __launch_bounds__(256,2) void attn_mfma_k(
    const _Float16* __restrict__ qkvH, const _Float16* __restrict__ qkvL,
    const float* __restrict__ mask,
    _Float16* __restrict__ ctxH, _Float16* __restrict__ ctxL)
{
  __shared__ _Float16 Kh[64][72], Kl[64][72];
  __shared__ _Float16 Vh[64][72], Vl[64][72];   // transposed: [d][k]
  __shared__ float msk[64];
  __shared__ float rsi[4][32];
  const int qb = blockIdx.x, h = blockIdx.y, b = blockIdx.z;
  const int tid = threadIdx.x;
  const int l = tid & 63, w = tid >> 6;
  const int l31 = l & 31, g5 = l >> 5;
  const float SC = 1.0f/8388608.0f;   // 2^-20 (split scale) * 1/8 (1/sqrt(64))

  u32x4 qfh[4], qfl[4];
  {
    const size_t qoff = (size_t)(b*Sq + qb*128 + w*32 + l31) * 2304 + h*DHq + g5*8;
    #pragma unroll
    for (int c = 0; c < 4; c++){
      qfh[c] = *(const u32x4*)(qkvH + qoff + c*16);
      qfl[c] = *(const u32x4*)(qkvL + qoff + c*16);
    }
  }
  f32x16 oacc[2];
  #pragma unroll
  for (int nt = 0; nt < 2; nt++)
    #pragma unroll
    for (int i = 0; i < 16; i++) oacc[nt][i] = 0.f;
  float rsl = 0.f;
  const float* mrow = mask + b*Sq;

  for (int kt = 0; kt < 8; kt++){
    __syncthreads();
    {
      const size_t krow = (size_t)(b*Sq + kt*64 + l) * 2304 + 768 + h*DHq;
      #pragma unroll
      for (int i = 0; i < 2; i++){
        const int ch = w + i*4;
        *(u32x4*)&Kh[l][ch*8] = *(const u32x4*)(qkvH + krow + ch*8);
        *(u32x4*)&Kl[l][ch*8] = *(const u32x4*)(qkvL + krow + ch*8);
      }
      const size_t vrow = krow + 768 + w*16;
      f16x8 v0 = __builtin_bit_cast(f16x8, *(const u32x4*)(qkvH + vrow));
      f16x8 v1 = __builtin_bit_cast(f16x8, *(const u32x4*)(qkvH + vrow + 8));
      f16x8 u0 = __builtin_bit_cast(f16x8, *(const u32x4*)(qkvL + vrow));
      f16x8 u1 = __builtin_bit_cast(f16x8, *(const u32x4*)(qkvL + vrow + 8));
      #pragma unroll
      for (int i = 0; i < 8; i++){
        Vh[w*16 + i][l] = v0[i]; Vh[w*16 + 8 + i][l] = v1[i];
        Vl[w*16 + i][l] = u0[i]; Vl[w*16 + 8 + i][l] = u1[i];
      }
      if (tid < 64) msk[tid] = mrow[kt*64 + tid] + 6.9314718055994531f; // + ln(1024)
    }
    __syncthreads();

    f32x16 sacc[2];
    #pragma unroll
    for (int mt = 0; mt < 2; mt++)
      #pragma unroll
      for (int i = 0; i < 16; i++) sacc[mt][i] = 0.f;
    #pragma unroll
    for (int mt = 0; mt < 2; mt++){
      #pragma unroll
      for (int c = 0; c < 4; c++){
        f16x8 kh = __builtin_bit_cast(f16x8, *(const u32x4*)&Kh[mt*32 + l31][c*16 + g5*8]);
        f16x8 kl = __builtin_bit_cast(f16x8, *(const u32x4*)&Kl[mt*32 + l31][c*16 + g5*8]);
        f16x8 qh = __builtin_bit_cast(f16x8, qfh[c]);
        f16x8 ql = __builtin_bit_cast(f16x8, qfl[c]);
        sacc[mt] = __builtin_amdgcn_mfma_f32_32x32x16_f16(kh, qh, sacc[mt], 0, 0, 0);
        sacc[mt] = __builtin_amdgcn_mfma_f32_32x32x16_f16(kh, ql, sacc[mt], 0, 0, 0);
        sacc[mt] = __builtin_amdgcn_mfma_f32_32x32x16_f16(kl, qh, sacc[mt], 0, 0, 0);
      }
    }

    unsigned int hP[2][4][2], lP[2][4][2];
    #pragma unroll
    for (int mt = 0; mt < 2; mt++){
      #pragma unroll
      for (int m = 0; m < 4; m++){
        f32x4 mk = *(const f32x4*)&msk[mt*32 + m*8 + g5*4];
        float p0 = __expf(fmaf(sacc[mt][4*m+0], SC, mk[0]));
        float p1 = __expf(fmaf(sacc[mt][4*m+1], SC, mk[1]));
        float p2 = __expf(fmaf(sacc[mt][4*m+2], SC, mk[2]));
        float p3 = __expf(fmaf(sacc[mt][4*m+3], SC, mk[3]));
        rsl += (p0 + p1) + (p2 + p3);
        f16x2 h0 = cvt_pk(p0, p1);
        f16x2 h1 = cvt_pk(p2, p3);
        f16x2 e0, e1;
        e0[0] = (_Float16)(p0 - (float)h0[0]); e0[1] = (_Float16)(p1 - (float)h0[1]);
        e1[0] = (_Float16)(p2 - (float)h1[0]); e1[1] = (_Float16)(p3 - (float)h1[1]);
        hP[mt][m][0] = __builtin_bit_cast(unsigned int, h0);
        hP[mt][m][1] = __builtin_bit_cast(unsigned int, h1);
        lP[mt][m][0] = __builtin_bit_cast(unsigned int, e0);
        lP[mt][m][1] = __builtin_bit_cast(unsigned int, e1);
      }
    }

    #pragma unroll
    for (int mt = 0; mt < 2; mt++){
      #pragma unroll
      for (int cc = 0; cc < 2; cc++){
        i32x2 sh0 = pl32swap(hP[mt][2*cc][0], hP[mt][2*cc+1][0]);
        i32x2 sh1 = pl32swap(hP[mt][2*cc][1], hP[mt][2*cc+1][1]);
        i32x2 sl0 = pl32swap(lP[mt][2*cc][0], lP[mt][2*cc+1][0]);
        i32x2 sl1 = pl32swap(lP[mt][2*cc][1], lP[mt][2*cc+1][1]);
        u32x4 pah = (u32x4){(unsigned)sh0[0], (unsigned)sh1[0], (unsigned)sh0[1], (unsigned)sh1[1]};
        u32x4 pal = (u32x4){(unsigned)sl0[0], (unsigned)sl1[0], (unsigned)sl0[1], (unsigned)sl1[1]};
        f16x8 ph = __builtin_bit_cast(f16x8, pah);
        f16x8 pe = __builtin_bit_cast(f16x8, pal);
        const int kof = (mt*2 + cc)*16 + g5*8;
        #pragma unroll
        for (int nt = 0; nt < 2; nt++){
          f16x8 vh = __builtin_bit_cast(f16x8, *(const u32x4*)&Vh[nt*32 + l31][kof]);
          f16x8 vl = __builtin_bit_cast(f16x8, *(const u32x4*)&Vl[nt*32 + l31][kof]);
          oacc[nt] = __builtin_amdgcn_mfma_f32_32x32x16_f16(ph, vh, oacc[nt], 0, 0, 0);
          oacc[nt] = __builtin_amdgcn_mfma_f32_32x32x16_f16(ph, vl, oacc[nt], 0, 0, 0);
          oacc[nt] = __builtin_amdgcn_mfma_f32_32x32x16_f16(pe, vh, oacc[nt], 0, 0, 0);
        }
      }
    }
  }

  {
    unsigned int rb = __builtin_bit_cast(unsigned int, rsl);
    i32x2 sw = pl32swap(rb, rb);
    float partner = __builtin_bit_cast(float, (l >= 32) ? sw[0] : sw[1]);
    float tot = rsl + partner;
    if (l < 32) rsi[w][l31] = 1.0f / tot;
  }
  __syncthreads();

  const size_t obase = (size_t)(b*Sq + qb*128 + w*32);
  #pragma unroll
  for (int nt = 0; nt < 2; nt++){
    const int col = h*DHq + nt*32 + l31;
    #pragma unroll
    for (int r = 0; r < 16; r++){
      const int q = (r&3) + 8*(r>>2) + 4*g5;
      const float v = oacc[nt][r] * rsi[w][q];
      const _Float16 hi = (_Float16)v;
      const size_t off = (obase + q)*Dq + col;
      ctxH[off] = hi;
      ctxL[off] = (_Float16)(v - (float)hi);
    }
  }
}

// ---------------- transpose + f32->bf16 (FFN weights -> [N][K] bf16) ----------------
__global__ void transpose_bf16_k(const float* __restrict__ src, unsigned short* __restrict__ dst,
                                 int K, int N)
{
  __shared__ float t[64][65];
  const int tid = threadIdx.x;
  const size_t mo = (size_t)blockIdx.z * K * N;
  const int k0 = blockIdx.y * 64, n0 = blockIdx.x * 64;
  const int r = tid >> 2, c0 = (tid & 3) * 16;
  const float* sp = src + mo + (size_t)(k0 + r) * N + n0 + c0;
  #pragma unroll
  for (int cc = 0; cc < 16; cc += 4){
    f32x4 v = *(const f32x4*)(sp + cc);
    t[r][c0+cc] = v[0]; t[r][c0+cc+1] = v[1]; t[r][c0+cc+2] = v[2]; t[r][c0+cc+3] = v[3];
  }
  __syncthreads();
  unsigned short* dp = dst + mo + (size_t)(n0 + r) * K + k0 + c0;
  u32x4 h0, h1v;
  #pragma unroll
  for (int i = 0; i < 4; i++) h0[i]  = pk2(t[c0+2*i  ][r], t[c0+2*i+1][r]);
  #pragma unroll
  for (int i = 0; i < 4; i++) h1v[i] = pk2(t[c0+8+2*i][r], t[c0+9+2*i][r]);
  *(u32x4*)(dp)     = h0;
  *(u32x4*)(dp + 8) = h1v;
}

// ------- bf16 MFMA GEMM (FFN path), all-DMA double-buffered staging -------
// Same LDS XOR-deswizzle as gemm_f16s_k (pre-swizzled DMA source + swizzled frag read).
// MT: 128 or 64 row tile. GATHER: A rows via tok_idx.
// OMODE: 0 bf16 store; 1 f32 accumulate (Cf += v); 2 f32 scatter add gate*(v) via tok_idx
template<int MT, bool GATHER, int OMODE, bool GELU_, bool GROUPED>
__global__ __launch_bounds__(256,2) void gemm_bf16_k(
    const unsigned short* __restrict__ A, const unsigned short* __restrict__ BT,
    const float* __restrict__ bias, float* __restrict__ Cf, unsigned short* __restrict__ Cb,
    int N, int K,
    const int* __restrict__ tile_g, const int* __restrict__ tile_r0,
    const int* __restrict__ grp_off, const int* __restrict__ n_tiles,
    const int* __restrict__ tok_idx, const float* __restrict__ gate_s,
    size_t bstride, int bias_stride)
{
  constexpr int MI = MT / 32;            // acc rows per wave
  constexpr int AI = MT / 64;            // A DMA instrs per wave
  __shared__ unsigned short As[2][MT][32];
  __shared__ unsigned short Bs[2][128][32];
  const int tid = threadIdx.x;
  const int lane = tid & 63, wave = tid >> 6;
  const int wm = wave >> 1, wn = wave & 1;
  int col0, row0, gend = 1 << 30, g = 0;
  if constexpr (GROUPED){
    const int gx = gridDim.x;
    const int nb = gx * gridDim.y;
    const int bid = blockIdx.y * gx + blockIdx.x;
    int lb = bid;
    if ((nb & 7) == 0) lb = (bid & 7) * (nb >> 3) + (bid >> 3);
    const int t = lb / gx;
    col0 = (lb - t * gx) * 128;
    if (t >= *n_tiles) return;
    g = tile_g[t];
    row0 = grp_off[g] + tile_r0[t];
    gend = grp_off[g+1];
  } else {
    int bx, by; swz2d(bx, by);
    row0 = by * MT;
    col0 = bx * 128;
  }
  const unsigned short* Bp = BT + (size_t)g * bstride;
  const float* bp = bias + (size_t)g * bias_stride;

  const int lr = lane >> 2;
  const int lk8 = (((lane & 3) ^ ((lane >> 3) & 3)) * 8);
  const unsigned short* pB[2];
  #pragma unroll
  for (int j = 0; j < 2; j++){
    const int ib = wave*2 + j;
    pB[j] = Bp + (size_t)(col0 + ib*16 + lr)*K + lk8;
  }
  auto stageB = [&](int c, int kk){
    gl_lds16(pB[0] + kk, &Bs[0][0][0] + c*4096 + (wave*2+0)*512);
    gl_lds16(pB[1] + kk, &Bs[0][0][0] + c*4096 + (wave*2+1)*512);
  };
  const unsigned short* pA[AI];
  #pragma unroll
  for (int j = 0; j < AI; j++){
    int r = row0 + (wave*AI + j)*16 + lr;
    if constexpr (GROUPED) r = (r < gend - 1) ? r : (gend - 1);
    if constexpr (GATHER) r = tok_idx[r];
    pA[j] = A + (size_t)r*K + lk8;
  }
  auto stageA = [&](int c, int kk){
    #pragma unroll
    for (int j = 0; j < AI; j++)
      gl_lds16(pA[j] + kk, &As[0][0][0] + c*(MT*32) + (wave*AI + j)*512);
  };
  const int fc = (((lane >> 4) ^ ((lane >> 1) & 3)) * 8);
  const int fr = lane & 15;

  f32x4 acc[MI][4];
  #pragma unroll
  for (int mi=0;mi<MI;mi++)
    #pragma unroll
    for (int ni=0;ni<4;ni++) acc[mi][ni] = (f32x4){0.f,0.f,0.f,0.f};

  const int nt = K >> 5;
  stageA(0, 0);
  stageB(0, 0);

  int cur = 0;
  for (int t = 0; t < nt; t++){
    __syncthreads();                      // tile t ready
    const int k1 = (t + 1) << 5;
    if (t + 1 < nt){
      stageA(cur ^ 1, k1);
      stageB(cur ^ 1, k1);
    }
    bf16x8 af[MI], bfr[4];
    #pragma unroll
    for (int mi=0;mi<MI;mi++){
      u32x4 tt = *(const u32x4*)&As[cur][wm*(MT/2) + mi*16 + fr][fc];
      af[mi] = __builtin_bit_cast(bf16x8, tt);
    }
    #pragma unroll
    for (int ni=0;ni<4;ni++){
      u32x4 tt = *(const u32x4*)&Bs[cur][wn*64 + ni*16 + fr][fc];
      bfr[ni] = __builtin_bit_cast(bf16x8, tt);
    }
    #pragma unroll
    for (int mi=0;mi<MI;mi++)
      #pragma unroll
      for (int ni=0;ni<4;ni++)
        acc[mi][ni] = __builtin_amdgcn_mfma_f32_16x16x32_bf16(af[mi], bfr[ni], acc[mi][ni], 0, 0, 0);
    cur ^= 1;
  }

  const int erow = 4*(lane >> 4);
  const int ecol = lane & 15;
  #pragma unroll
  for (int mi=0;mi<MI;mi++)
    #pragma unroll
    for (int ni=0;ni<4;ni++){
      const int c = col0 + wn*64 + ni*16 + ecol;
      const float bb = bp[c];
      #pragma unroll
      for (int r=0;r<4;r++){
        const int R = row0 + wm*(MT/2) + mi*16 + erow + r;
        if (GROUPED && R >= gend) continue;
        float v = acc[mi][ni][r] + bb;
        if (GELU_) v = 0.5f*v*(1.0f + erff(v*0.70710678118654752f));
        if constexpr (OMODE == 0){
          Cb[(size_t)R*N + c] = f2bf(v);
        } else if constexpr (OMODE == 1){
          Cf[(size_t)R*N + c] += v;
        } else {
          const int tok = tok_idx[R];
          const float gt = gate_s[R];
          float* p = Cf + (size_t)tok*N + c;
          *p += gt*v;
        }
      }
    }
}

// ---------------- token-level switch router (f32, one wave/token) ----------------
__global__ void token_router_k(const float* __restrict__ att, const int* __restrict__ sel,
    const float* __restrict__ sww, const float* __restrict__ swb,
    int* __restrict__ grp, float* __restrict__ gate, int* __restrict__ grp_cnt)
{
  const int t = blockIdx.x*4 + (threadIdx.x >> 6);
  const int lane = threadIdx.x & 63;
  const int e = sel[t >> 9];
  const float* x = att + (size_t)t * Dq;
  const float* w = sww + (size_t)e * Dq * 4;
  float a0=0.f, a1=0.f, a2=0.f, a3=0.f;
  #pragma unroll 4
  for (int i = 0; i < 12; i++){
    const int d = lane + i*64;
    const float xv = x[d];
    f32x4 wv = *(const f32x4*)&w[d*4];
    a0 += xv*wv[0]; a1 += xv*wv[1]; a2 += xv*wv[2]; a3 += xv*wv[3];
  }
  #pragma unroll
  for (int off = 32; off; off >>= 1){
    a0 += __shfl_xor(a0, off); a1 += __shfl_xor(a1, off);
    a2 += __shfl_xor(a2, off); a3 += __shfl_xor(a3, off);
  }
  if (lane == 0){
    const float l0 = a0 + swb[e*4+0], l1 = a1 + swb[e*4+1];
    const float l2 = a2 + swb[e*4+2], l3 = a3 + swb[e*4+3];
    const float mx = fmaxf(fmaxf(l0,l1), fmaxf(l2,l3));
    const float p0 = expf(l0-mx), p1 = expf(l1-mx), p2 = expf(l2-mx), p3 = expf(l3-mx);
    const float ssum = p0+p1+p2+p3;
    int am = 0; float bv = p0;
    if (p1 > bv){ bv=p1; am=1; }
    if (p2 > bv){ bv=p2; am=2; }
    if (p3 > bv){ bv=p3; am=3; }
    grp[t] = e*4 + am;
    gate[t] = bv/ssum;
    atomicAdd(&grp_cnt[e*4 + am], 1);
  }
}

__global__ void build_offsets_k(const int* __restrict__ grp_cnt, int* __restrict__ grp_off,
    int* __restrict__ tg128, int* __restrict__ tr128, int* __restrict__ nt128,
    int* __restrict__ tg64, int* __restrict__ tr64, int* __restrict__ nt64)
{
  int off = 0, n1 = 0, n2 = 0;
  for (int g = 0; g < 16; g++){
    grp_off[g] = off;
    const int c = grp_cnt[g];
    for (int r0 = 0; r0 < c; r0 += 128){ tg128[n1] = g; tr128[n1] = r0; n1++; }
    for (int r0 = 0; r0 < c; r0 += 64){  tg64[n2]  = g; tr64[n2]  = r0; n2++; }
    off += c;
  }
  grp_off[16] = off;
  *nt128 = n1; *nt64 = n2;
}

__global__ void scatter_k(const int* __restrict__ grp, const float* __restrict__ gate,
    const int* __restrict__ grp_off, int* __restrict__ fill,
    int* __restrict__ tok_idx, float* __restrict__ gate_s)
{
  const int t = blockIdx.x*256 + threadIdx.x;
  const int g = grp[t];
  const int pos = grp_off[g] + atomicAdd(&fill[g], 1);
  tok_idx[pos] = t;
  gate_s[pos] = gate[t];
}

// ---------------- final LayerNorm (att already holds att+ffn) ----------------
__global__ __launch_bounds__(256) void final_ln_k(const float* __restrict__ att,
    const float* __restrict__ lg, const float* __restrict__ lb, float* __restrict__ out)
{
  const int row = blockIdx.x, tid = threadIdx.x;
  const float* a = att + (size_t)row * Dq;
  float x[3];
  #pragma unroll
  for (int i = 0; i < 3; i++) x[i] = a[tid + 256*i];
  __shared__ float red[256];
  red[tid] = x[0] + x[1] + x[2];
  __syncthreads();
  for (int st = 128; st; st >>= 1){
    if (tid < st) red[tid] += red[tid + st];
    __syncthreads();
  }
  const float mu = red[0] * (1.0f/768.0f);
  __syncthreads();
  const float d0 = x[0]-mu, d1 = x[1]-mu, d2 = x[2]-mu;
  red[tid] = d0*d0 + d1*d1 + d2*d2;
  __syncthreads();
  for (int st = 128; st; st >>= 1){
    if (tid < st) red[tid] += red[tid + st];
    __syncthreads();
  }
  const float inv = 1.0f/sqrtf(red[0]*(1.0f/768.0f) + 1e-12f);
  #pragma unroll
  for (int i = 0; i < 3; i++){
    const int col = tid + 256*i;
    out[(size_t)row*Dq + col] = (x[i]-mu)*inv*lg[col] + lb[col];
  }
}

// ======================= launch =======================
extern "C" void kernel_launch(void* const* d_in, const int* in_sizes, int n_in,
                              void* d_out, int out_size, void* d_ws, size_t ws_size,
                              hipStream_t stream)
{
  (void)in_sizes; (void)n_in; (void)out_size; (void)ws_size;
  const float* hs    = (const float*)d_in[0];
  const float* amask = (const float*)d_in[1];
  const float* sw_enc_w = (const float*)d_in[3];
  const float* sw_enc_b = (const float*)d_in[4];
  const float* sw_w  = (const float*)d_in[5];
  const float* sw_b  = (const float*)d_in[6];
  const float* ca_wq = (const float*)d_in[7];
  const float* ca_bq = (const float*)d_in[8];
  const float* ca_wk = (const float*)d_in[9];
  const float* ca_bk = (const float*)d_in[10];
  const float* ca_wv = (const float*)d_in[11];
  const float* ca_bv = (const float*)d_in[12];
  const float* ca_wo = (const float*)d_in[13];
  const float* ca_bo = (const float*)d_in[14];
  const float* ua_wq = (const float*)d_in[15];
  const float* ua_bq = (const float*)d_in[16];
  const float* ua_wk = (const float*)d_in[17];
  const float* ua_bk = (const float*)d_in[18];
  const float* ua_wv = (const float*)d_in[19];
  const float* ua_bv = (const float*)d_in[20];
  const float* ua_wo = (const float*)d_in[21];
  const float* ua_bo = (const float*)d_in[22];
  const float* cf_w1 = (const float*)d_in[23];
  const float* cf_b1 = (const float*)d_in[24];
  const float* cf_w2 = (const float*)d_in[25];
  const float* cf_b2 = (const float*)d_in[26];
  const float* uf_sw_w = (const float*)d_in[27];
  const float* uf_sw_b = (const float*)d_in[28];
  const float* uf_w1 = (const float*)d_in[29];
  const float* uf_b1 = (const float*)d_in[30];
  const float* uf_w2 = (const float*)d_in[31];
  const float* uf_b2 = (const float*)d_in[32];
  const float* ln_g  = (const float*)d_in[33];
  const float* ln_b  = (const float*)d_in[34];
  float* out = (float*)d_out;

  char* W = (char*)d_ws;
  // control block
  int*   sel     = (int*)(W + 0);
  float* pm      = (float*)(W + 64);
  int*   grp_cnt = (int*)(W + 128);
  int*   fill    = (int*)(W + 192);
  int*   ntile   = (int*)(W + 256);
  int*   ntile64 = (int*)(W + 320);
  int*   grp_off = (int*)(W + 512);
  int*   tile_g  = (int*)(W + 1024);
  int*   tile_r  = (int*)(W + 2048);
  int*   tile_g64= (int*)(W + 3072);
  int*   tile_r64= (int*)(W + 4096);

  float* att = (float*)(W + 8192);                        // [8192][768] f32, holds att then att+ffn
  unsigned short* attb = (unsigned short*)(W + 25174016); // [8192][768] bf16 snapshot
  const size_t X = 50339840;
  _Float16* hsH  = (_Float16*)(W + X);                 // 12,582,912
  _Float16* hsL  = (_Float16*)(W + X + 12582912);
  _Float16* qkvH = (_Float16*)(W + X + 25165824);      // 37,748,736
  _Float16* qkvL = (_Float16*)(W + X + 62914560);      // end X+100663296
  _Float16* ctxH = (_Float16*)(W + X + 100663296);     // 12,582,912
  _Float16* ctxL = (_Float16*)(W + X + 113246208);     // end X+125829120
  _Float16* wqkv_cH = (_Float16*)(W + X + 125829120);  // 3,538,944
  _Float16* wqkv_cL = (_Float16*)(W + X + 129368064);
  _Float16* wqkv_uH = (_Float16*)(W + X + 132907008);  // 14,155,776
  _Float16* wqkv_uL = (_Float16*)(W + X + 147062784);
  _Float16* wo_cH   = (_Float16*)(W + X + 161218560);  // 1,179,648
  _Float16* wo_cL   = (_Float16*)(W + X + 162398208);
  _Float16* wo_uH   = (_Float16*)(W + X + 163577856);  // 4,718,592
  _Float16* wo_uL   = (_Float16*)(W + X + 168296448);  // end X+173015040
  float* qkvb_c = (float*)(W + X + 173015040);         // 9,216
  float* qkvb_u = (float*)(W + X + 173024256);         // 36,864
  float* partb  = (float*)(W + X + 173061120);         // 196,608

  // phase B (after attention) reuses phase-A scratch:
  unsigned short* w1T = (unsigned short*)(W + X);              // 80,216,064
  unsigned short* w2T = (unsigned short*)(W + X + 80216064);   // end X+160432128
  unsigned short* h1  = (unsigned short*)(W + X + 160432128);  // 50,331,648
  int*   grp     = (int*)(W + 261103616);
  float* gate    = (float*)(W + 261136384);
  int*   tok_idx = (int*)(W + 261169152);
  float* gate_s  = (float*)(W + 261201920);

  hipMemsetAsync(W, 0, 512, stream);

  // ---- sequence router (exact f32) ----
  pooled_partial_k<<<dim3(Bq,3,4),256,0,stream>>>(hs, partb);
  router_seq_k<<<Bq,128,0,stream>>>(partb, sw_enc_w, sw_enc_b, sw_w, sw_b, sel, pm);

  // ---- prepare split-f16 operands ----
  split_f16_k<<<6144,256,0,stream>>>(hs, hsH, hsL, NTq*Dq/4);
  transpose_f16s_k<<<dim3(12,12,1),256,0,stream>>>(ca_wq, wqkv_cH, wqkv_cL, Dq, Dq, 0, 0, 0);
  transpose_f16s_k<<<dim3(12,12,1),256,0,stream>>>(ca_wk, wqkv_cH, wqkv_cL, Dq, Dq, 0, 0, 768);
  transpose_f16s_k<<<dim3(12,12,1),256,0,stream>>>(ca_wv, wqkv_cH, wqkv_cL, Dq, Dq, 0, 0, 1536);
  transpose_f16s_k<<<dim3(12,12,4),256,0,stream>>>(ua_wq, wqkv_uH, wqkv_uL, Dq, Dq, (long)Dq*Dq, (long)2304*768, 0);
  transpose_f16s_k<<<dim3(12,12,4),256,0,stream>>>(ua_wk, wqkv_uH, wqkv_uL, Dq, Dq, (long)Dq*Dq, (long)2304*768, 768);
  transpose_f16s_k<<<dim3(12,12,4),256,0,stream>>>(ua_wv, wqkv_uH, wqkv_uL, Dq, Dq, (long)Dq*Dq, (long)2304*768, 1536);
  transpose_f16s_k<<<dim3(12,12,1),256,0,stream>>>(ca_wo, wo_cH, wo_cL, Dq, Dq, 0, 0, 0);
  transpose_f16s_k<<<dim3(12,12,4),256,0,stream>>>(ua_wo, wo_uH, wo_uL, Dq, Dq, (long)Dq*Dq, (long)Dq*Dq, 0);
  concat_bias3_k<<<dim3(3,1),256,0,stream>>>(ca_bq, ca_bk, ca_bv, qkvb_c, 0);
  concat_bias3_k<<<dim3(3,4),256,0,stream>>>(ua_bq, ua_bk, ua_bv, qkvb_u, 768);

  // ---- common attention ----
  gemm_f16s_k<128,0,2><<<dim3(18,64),256,0,stream>>>(hsH, hsL, wqkv_cH, wqkv_cL, qkvb_c,
      nullptr, qkvH, qkvL, nullptr, 2304, Dq, 0, 0, nullptr, nullptr);
  attn_mfma_k<<<dim3(4,Hq,Bq),256,0,stream>>>(qkvH, qkvL, amask, ctxH, ctxL);
  gemm_f16s_k<64,0,0><<<dim3(6,128),256,0,stream>>>(ctxH, ctxL, wo_cH, wo_cL, ca_bo,
      att, nullptr, nullptr, attb, Dq, Dq, 0, 0, nullptr, nullptr);

  // ---- unique attention (selected expert), att += pm * result ----
  gemm_f16s_k<128,1,2><<<dim3(18,64),256,0,stream>>>(hsH, hsL, wqkv_uH, wqkv_uL, qkvb_u,
      nullptr, qkvH, qkvL, nullptr, 2304, Dq, (long)2304*768, 2304, sel, nullptr);
  attn_mfma_k<<<dim3(4,Hq,Bq),256,0,stream>>>(qkvH, qkvL, amask, ctxH, ctxL);
  gemm_f16s_k<64,1,1><<<dim3(6,128),256,0,stream>>>(ctxH, ctxL, wo_uH, wo_uL, ua_bo,
      att, nullptr, nullptr, attb, Dq, Dq, (long)Dq*Dq, Dq, sel, pm);

  // ---- token routing on pristine f32 att (before in-place FFN accumulate) ----
  token_router_k<<<2048,256,0,stream>>>(att, sel, uf_sw_w, uf_sw_b, grp, gate, grp_cnt);
  build_offsets_k<<<1,1,0,stream>>>(grp_cnt, grp_off, tile_g, tile_r, ntile, tile_g64, tile_r64, ntile64);
  scatter_k<<<32,256,0,stream>>>(grp, gate, grp_off, fill, tok_idx, gate_s);

  // ---- FFN weights -> transposed bf16 (phase-A scratch now free) ----
  transpose_bf16_k<<<dim3(48,12,1), 256,0,stream>>>(cf_w1, w1T, Dq, Fq);
  transpose_bf16_k<<<dim3(48,12,16),256,0,stream>>>(uf_w1, w1T + 2359296, Dq, Fq);
  transpose_bf16_k<<<dim3(12,48,1), 256,0,stream>>>(cf_w2, w2T, Fq, Dq);
  transpose_bf16_k<<<dim3(12,48,16),256,0,stream>>>(uf_w2, w2T + 2359296, Fq, Dq);

  // ---- common FFN (bf16 MFMA, all-DMA) ----
  gemm_bf16_k<128,false,0,true,false><<<dim3(24,64),256,0,stream>>>(attb, w1T, cf_b1, nullptr, h1,
      Fq, Dq, nullptr,nullptr,nullptr,nullptr,nullptr,nullptr, (size_t)0, 0);
  gemm_bf16_k<64,false,1,false,false><<<dim3(6,128),256,0,stream>>>(h1, w2T, cf_b2, att, nullptr,
      Dq, Fq, nullptr,nullptr,nullptr,nullptr,nullptr,nullptr, (size_t)0, 0);

  // ---- unique FFN (grouped, top-1 inner expert, gated scatter-add into att) ----
  gemm_bf16_k<128,true,0,true,true><<<dim3(24,80),256,0,stream>>>(attb, w1T + 2359296, uf_b1, nullptr, h1,
      Fq, Dq, tile_g, tile_r, grp_off, ntile, tok_idx, gate_s, (size_t)2359296, Fq);
  gemm_bf16_k<64,false,2,false,true><<<dim3(6,144),256,0,stream>>>(h1, w2T + 2359296, uf_b2, att, nullptr,
      Dq, Fq, tile_g64, tile_r64, grp_off, ntile64, tok_idx, gate_s, (size_t)2359296, Dq);

  // ---- LayerNorm (att holds residual+ffn) ----
  final_ln_k<<<NTq,256,0,stream>>>(att, ln_g, ln_b, out);
}